// Round 4
// baseline (534.226 us; speedup 1.0000x reference)
//
#include <hip/hip_runtime.h>
#include <hip/hip_bf16.h>
#include <math.h>

// Problem constants
#define B_N 4096
#define BITSN 64
#define HID 512
#define EPSV 1e-5f
#define BT 16   // batch rows per shift2 block

typedef unsigned short ushort_t;
typedef __attribute__((ext_vector_type(8))) short bf16x8;
typedef __attribute__((ext_vector_type(4))) float f32x4;

__device__ __forceinline__ ushort_t f2bf(float f) {
  unsigned u = __float_as_uint(f);
  u += 0x7FFF + ((u >> 16) & 1);   // round-to-nearest-even
  return (ushort_t)(u >> 16);
}

__device__ __forceinline__ unsigned pack2bf(float lo, float hi) {
  union { __hip_bfloat162 h; unsigned u; } cv;
  cv.h = __float22bfloat162_rn(make_float2(lo, hi));  // v_cvt_pk_bf16_f32
  return cv.u;
}

// ---------------- prep: bf16 copies + transposes ----------------
__global__ __launch_bounds__(256) void prep_kernel(
    const float* __restrict__ Wi2, const float* __restrict__ Wi3,
    const float* __restrict__ Wi1, const float* __restrict__ W1,
    const float* __restrict__ W2, const float* __restrict__ W3,
    ushort_t* __restrict__ Wi2b, ushort_t* __restrict__ Wi3b,
    float* __restrict__ Wi1posT, ushort_t* __restrict__ W1b,
    ushort_t* __restrict__ W2b, ushort_t* __restrict__ W3b,
    ushort_t* __restrict__ Wi1sb) {
  int idx = blockIdx.x * 256 + threadIdx.x;
  if (idx < 512 * 512) {
    Wi2b[idx] = f2bf(Wi2[idx]);
    W2b[idx] = f2bf(W2[idx]);
  }
  if (idx < 64 * 512) {
    Wi3b[idx] = f2bf(Wi3[idx]);
    W3b[idx] = f2bf(W3[idx]);
    int p = idx >> 9, i = idx & 511;
    Wi1posT[idx] = Wi1[i * 128 + p];   // pos_part[p][i] = Wi1[i][p]
  }
  if (idx < 512 * 64) {
    W1b[idx] = f2bf(W1[idx]);                       // [512][64]
    int j = idx >> 6, k = idx & 63;
    Wi1sb[idx] = f2bf(Wi1[j * 128 + 64 + k]);       // shift cols of Wi1: [512][64]
  }
}

// ---------------- shift decoder, MFMA-batched: 16 rows/block ----------------
__global__ __launch_bounds__(256) void shift2_kernel(
    const float* __restrict__ shift_bits,
    const ushort_t* __restrict__ W1b, const float* __restrict__ b1,
    const float* __restrict__ g1, const float* __restrict__ be1,
    const ushort_t* __restrict__ W2b, const float* __restrict__ b2,
    const float* __restrict__ g2, const float* __restrict__ be2,
    const ushort_t* __restrict__ W3b, const float* __restrict__ b3,
    const ushort_t* __restrict__ Wi1sb, const float* __restrict__ bi1,
    float* __restrict__ sp) {
  __shared__ __align__(16) ushort_t hA[BT * 512];     // 16KB: h1 (post LN1+relu)
  __shared__ __align__(16) char reg2[32 * 1024];      // phase union
  __shared__ float b1s[512], g1s[512], be1s[512];
  __shared__ float b2s[512], g2s[512], be2s[512], bi1s[512];
  __shared__ float red[4][BT][2];
  __shared__ float b3s[64];

  ushort_t* sbt = (ushort_t*)reg2;                    // phase 1: shift_bits tile [16][64]
  ushort_t* Bs  = (ushort_t*)reg2;                    // phase 2: W2 tile [512][32]
  ushort_t* h2  = (ushort_t*)reg2;                    // phase 3: h2 [16][512]
  float (*lg32)[68] = (float(*)[68])(reg2 + 16 * 1024);
  ushort_t* sb2 = (ushort_t*)(reg2 + 16 * 1024 + 16 * 68 * 4);  // soft [16][64]

  int b0 = blockIdx.x * BT;
  int t = threadIdx.x, w = t >> 6, l = t & 63, lg = l >> 4, l15 = l & 15;

  b1s[t] = b1[t];  b1s[t + 256] = b1[t + 256];
  g1s[t] = g1[t];  g1s[t + 256] = g1[t + 256];
  be1s[t] = be1[t]; be1s[t + 256] = be1[t + 256];
  b2s[t] = b2[t];  b2s[t + 256] = b2[t + 256];
  g2s[t] = g2[t];  g2s[t + 256] = g2[t + 256];
  be2s[t] = be2[t]; be2s[t + 256] = be2[t + 256];
  bi1s[t] = bi1[t]; bi1s[t + 256] = bi1[t + 256];
  if (t < 64) b3s[t] = b3[t];
  if (t < 128) {   // stage shift_bits tile -> bf16 swizzled
    int row = t >> 3, g = t & 7;
    const float* src = shift_bits + (size_t)(b0 + row) * 64 + g * 8;
    uint4 pk;
    pk.x = (unsigned)f2bf(src[0]) | ((unsigned)f2bf(src[1]) << 16);
    pk.y = (unsigned)f2bf(src[2]) | ((unsigned)f2bf(src[3]) << 16);
    pk.z = (unsigned)f2bf(src[4]) | ((unsigned)f2bf(src[5]) << 16);
    pk.w = (unsigned)f2bf(src[6]) | ((unsigned)f2bf(src[7]) << 16);
    *(uint4*)((char*)sbt + ((row * 128 + g * 16) ^ ((row & 7) << 4))) = pk;
  }
  __syncthreads();

  // ----- GEMM1: x1[16][512] = sbt @ W1^T ; wave w owns cols [w*128, w*128+128) -----
  f32x4 acc[8];
#pragma unroll
  for (int nt = 0; nt < 8; ++nt) acc[nt] = (f32x4){0.f, 0.f, 0.f, 0.f};
#pragma unroll
  for (int ks = 0; ks < 2; ++ks) {
    bf16x8 af = *(const bf16x8*)((char*)sbt + ((l15 * 128 + ks * 64 + lg * 16) ^ ((l15 & 7) << 4)));
#pragma unroll
    for (int nt = 0; nt < 8; ++nt) {
      int c = w * 128 + nt * 16 + l15;
      bf16x8 bfr = *(const bf16x8*)(W1b + (size_t)c * 64 + ks * 32 + lg * 8);
      acc[nt] = __builtin_amdgcn_mfma_f32_16x16x32_bf16(af, bfr, acc[nt], 0, 0, 0);
    }
  }
  // ----- LN1 + relu -> hA -----
  {
    float s[4] = {0.f, 0.f, 0.f, 0.f}, q[4] = {0.f, 0.f, 0.f, 0.f};
#pragma unroll
    for (int nt = 0; nt < 8; ++nt) {
      int c = w * 128 + nt * 16 + l15;
      float bb = b1s[c];
#pragma unroll
      for (int r = 0; r < 4; ++r) {
        float x = acc[nt][r] + bb;
        acc[nt][r] = x;
        s[r] += x; q[r] += x * x;
      }
    }
#pragma unroll
    for (int m = 8; m >= 1; m >>= 1)
#pragma unroll
      for (int r = 0; r < 4; ++r) { s[r] += __shfl_xor(s[r], m); q[r] += __shfl_xor(q[r], m); }
    if (l15 == 0)
#pragma unroll
      for (int r = 0; r < 4; ++r) { red[w][4 * lg + r][0] = s[r]; red[w][4 * lg + r][1] = q[r]; }
    __syncthreads();
    float mean[4], rs[4];
#pragma unroll
    for (int r = 0; r < 4; ++r) {
      int p = 4 * lg + r;
      float S = red[0][p][0] + red[1][p][0] + red[2][p][0] + red[3][p][0];
      float Q = red[0][p][1] + red[1][p][1] + red[2][p][1] + red[3][p][1];
      mean[r] = S * (1.0f / 512.0f);
      float var = Q * (1.0f / 512.0f) - mean[r] * mean[r];
      rs[r] = rsqrtf(var + EPSV);
    }
#pragma unroll
    for (int nt = 0; nt < 8; ++nt) {
      int c = w * 128 + nt * 16 + l15;
      float gg = g1s[c], bb = be1s[c];
#pragma unroll
      for (int r = 0; r < 4; ++r) {
        int p = 4 * lg + r;
        float v = (acc[nt][r] - mean[r]) * rs[r] * gg + bb;
        v = v > 0.f ? v : 0.f;
        *(ushort_t*)((char*)hA + ((p * 1024 + c * 2) ^ ((p & 7) << 4))) = f2bf(v);
      }
    }
  }
  __syncthreads();

  // ----- GEMM2: x2[16][512] = hA @ W2^T, K=512 staged in 16 chunks of 32 -----
#pragma unroll
  for (int nt = 0; nt < 8; ++nt) acc[nt] = (f32x4){0.f, 0.f, 0.f, 0.f};
  for (int step = 0; step < 16; ++step) {
    int i0 = step * 32;
#pragma unroll
    for (int qq = 0; qq < 8; ++qq) {   // stage Bs [512][32] swizzled (linear writes)
      int g = qq * 256 + t;
      int c = g >> 2, xg = g & 3;
      int ic = xg ^ ((c >> 1) & 3);
      ((uint4*)Bs)[g] = *(const uint4*)(W2b + (size_t)c * 512 + i0 + ic * 8);
    }
    __syncthreads();
    bf16x8 af = *(const bf16x8*)((char*)hA + ((l15 * 1024 + step * 64 + lg * 16) ^ ((l15 & 7) << 4)));
#pragma unroll
    for (int nt = 0; nt < 8; ++nt) {
      int c = w * 128 + nt * 16 + l15;
      bf16x8 bfr = ((const bf16x8*)Bs)[c * 4 + (lg ^ ((c >> 1) & 3))];
      acc[nt] = __builtin_amdgcn_mfma_f32_16x16x32_bf16(af, bfr, acc[nt], 0, 0, 0);
    }
    __syncthreads();
  }
  // ----- LN2 + relu -> h2 (overwrites Bs region; safe: barrier above) -----
  {
    float s[4] = {0.f, 0.f, 0.f, 0.f}, q[4] = {0.f, 0.f, 0.f, 0.f};
#pragma unroll
    for (int nt = 0; nt < 8; ++nt) {
      int c = w * 128 + nt * 16 + l15;
      float bb = b2s[c];
#pragma unroll
      for (int r = 0; r < 4; ++r) {
        float x = acc[nt][r] + bb;
        acc[nt][r] = x;
        s[r] += x; q[r] += x * x;
      }
    }
#pragma unroll
    for (int m = 8; m >= 1; m >>= 1)
#pragma unroll
      for (int r = 0; r < 4; ++r) { s[r] += __shfl_xor(s[r], m); q[r] += __shfl_xor(q[r], m); }
    if (l15 == 0)
#pragma unroll
      for (int r = 0; r < 4; ++r) { red[w][4 * lg + r][0] = s[r]; red[w][4 * lg + r][1] = q[r]; }
    __syncthreads();
    float mean[4], rs[4];
#pragma unroll
    for (int r = 0; r < 4; ++r) {
      int p = 4 * lg + r;
      float S = red[0][p][0] + red[1][p][0] + red[2][p][0] + red[3][p][0];
      float Q = red[0][p][1] + red[1][p][1] + red[2][p][1] + red[3][p][1];
      mean[r] = S * (1.0f / 512.0f);
      float var = Q * (1.0f / 512.0f) - mean[r] * mean[r];
      rs[r] = rsqrtf(var + EPSV);
    }
#pragma unroll
    for (int nt = 0; nt < 8; ++nt) {
      int c = w * 128 + nt * 16 + l15;
      float gg = g2s[c], bb = be2s[c];
#pragma unroll
      for (int r = 0; r < 4; ++r) {
        int p = 4 * lg + r;
        float v = (acc[nt][r] - mean[r]) * rs[r] * gg + bb;
        v = v > 0.f ? v : 0.f;
        *(ushort_t*)((char*)h2 + ((p * 1024 + c * 2) ^ ((p & 7) << 4))) = f2bf(v);
      }
    }
  }
  __syncthreads();

  // ----- GEMM3: logits[16][64] = h2 @ W3^T ; wave w owns cols [16w,16w+16) -----
  {
    f32x4 a3 = (f32x4){0.f, 0.f, 0.f, 0.f};
#pragma unroll
    for (int ks = 0; ks < 16; ++ks) {
      bf16x8 af = *(const bf16x8*)((char*)h2 + ((l15 * 1024 + ks * 64 + lg * 16) ^ ((l15 & 7) << 4)));
      bf16x8 bfr = *(const bf16x8*)(W3b + (size_t)(w * 16 + l15) * 512 + ks * 32 + lg * 8);
      a3 = __builtin_amdgcn_mfma_f32_16x16x32_bf16(af, bfr, a3, 0, 0, 0);
    }
    int c = w * 16 + l15;
    float bb = b3s[c];
#pragma unroll
    for (int r = 0; r < 4; ++r) lg32[4 * lg + r][c] = a3[r] + bb;
  }
  __syncthreads();

  // ----- softmax over 64 logits -> sb2 (bf16, swizzled) -----
  {
    int r = t >> 4, j = t & 15;
    float v[4];
    float m = -1e30f;
#pragma unroll
    for (int mq = 0; mq < 4; ++mq) { v[mq] = lg32[r][mq * 16 + j]; m = fmaxf(m, v[mq]); }
#pragma unroll
    for (int mk = 8; mk >= 1; mk >>= 1) m = fmaxf(m, __shfl_xor(m, mk));
    float ssum = 0.f;
#pragma unroll
    for (int mq = 0; mq < 4; ++mq) { v[mq] = expf(v[mq] - m); ssum += v[mq]; }
#pragma unroll
    for (int mk = 8; mk >= 1; mk >>= 1) ssum += __shfl_xor(ssum, mk);
    float inv = 1.f / ssum;
#pragma unroll
    for (int mq = 0; mq < 4; ++mq) {
      int c = mq * 16 + j;
      *(ushort_t*)((char*)sb2 + ((r * 128 + c * 2) ^ ((r & 7) << 4))) = f2bf(v[mq] * inv);
    }
  }
  __syncthreads();

  // ----- GEMM4: sp[16][512] = soft @ Wi1shift^T + bi1 -----
  {
    f32x4 a4[8];
#pragma unroll
    for (int nt = 0; nt < 8; ++nt) a4[nt] = (f32x4){0.f, 0.f, 0.f, 0.f};
#pragma unroll
    for (int ks = 0; ks < 2; ++ks) {
      bf16x8 af = *(const bf16x8*)((char*)sb2 + ((l15 * 128 + ks * 64 + lg * 16) ^ ((l15 & 7) << 4)));
#pragma unroll
      for (int nt = 0; nt < 8; ++nt) {
        int c = w * 128 + nt * 16 + l15;
        bf16x8 bfr = *(const bf16x8*)(Wi1sb + (size_t)c * 64 + ks * 32 + lg * 8);
        a4[nt] = __builtin_amdgcn_mfma_f32_16x16x32_bf16(af, bfr, a4[nt], 0, 0, 0);
      }
    }
#pragma unroll
    for (int nt = 0; nt < 8; ++nt) {
      int c = w * 128 + nt * 16 + l15;
      float bb = bi1s[c];
#pragma unroll
      for (int r = 0; r < 4; ++r)
        sp[(size_t)(b0 + 4 * lg + r) * 512 + c] = a4[nt][r] + bb;
    }
  }
}

// ---------------- big3: flat-GEMM view, BM=128 (2 batch rows / block) ----------------
// M = 262144 rows (b*64+p), N = 512, K = 512. A-panel h1[128][512] computed ONCE
// into LDS (bf16, 16B-granule XOR swizzle: addr ^= (row&7)<<4). 8 waves; wave w
// owns rows [ (w>>2)*64, +64 ) x cols [ (w&3)*128, +128 ): acc 4x8 frags.
// B (Wi2b, 512KB) read directly from L2 as MFMA fragments (block-invariant -> hot).
// __launch_bounds__(512,2): up to 256 VGPR so compiler can pipeline B-fragments.
__global__ __launch_bounds__(512, 2) void big3_kernel(
    const float* __restrict__ a_bits, const float* __restrict__ sp,
    const float* __restrict__ Wi1posT,
    const ushort_t* __restrict__ Wi2b, const ushort_t* __restrict__ Wi3b,
    const float* __restrict__ bi2, const float* __restrict__ bi3,
    float* __restrict__ out) {
  __shared__ __align__(16) ushort_t h1s[128 * 512];   // 128KB, reused as h2
  __shared__ float bi2s[512];
  __shared__ float ab2[128];
  __shared__ float bi3s[64];

  int m0 = blockIdx.x * 128;
  int t = threadIdx.x, w = t >> 6, l = t & 63, lg = l >> 4, l15 = l & 15;

  bi2s[t] = bi2[t];
  if (t < 128) ab2[t] = a_bits[m0 + t];   // rows b0,b0+1 of a_bits, contiguous
  if (t < 64) bi3s[t] = bi3[t];

  // ---- phase 0: A-panel h1[128][512] = relu(sp[b(row)] + pos[row&63]) -> LDS, ONCE ----
  {
    int r = t >> 2, q = t & 3;             // row 0..127, col-chunk q*128..q*128+127
    int bl = r >> 6, p = r & 63;
    const float4* spp = (const float4*)(sp + (size_t)(blockIdx.x * 2 + bl) * 512 + q * 128);
    const float4* pp  = (const float4*)(Wi1posT + (size_t)p * 512 + q * 128);
#pragma unroll
    for (int j = 0; j < 16; ++j) {
      float4 s0 = spp[2 * j], s1 = spp[2 * j + 1];
      float4 p0 = pp[2 * j],  p1 = pp[2 * j + 1];
      float v0 = fmaxf(s0.x + p0.x, 0.f), v1 = fmaxf(s0.y + p0.y, 0.f);
      float v2 = fmaxf(s0.z + p0.z, 0.f), v3 = fmaxf(s0.w + p0.w, 0.f);
      float v4 = fmaxf(s1.x + p1.x, 0.f), v5 = fmaxf(s1.y + p1.y, 0.f);
      float v6 = fmaxf(s1.z + p1.z, 0.f), v7 = fmaxf(s1.w + p1.w, 0.f);
      uint4 pk;
      pk.x = pack2bf(v0, v1); pk.y = pack2bf(v2, v3);
      pk.z = pack2bf(v4, v5); pk.w = pack2bf(v6, v7);
      *(uint4*)((char*)h1s + ((r * 1024 + (q * 16 + j) * 16) ^ ((r & 7) << 4))) = pk;
    }
  }
  __syncthreads();

  // ---- GEMM1: h2[128][512] = h1 @ Wi2^T ; barrier-free K-loop, B from L2 ----
  int h = w >> 2, cq = w & 3;
  f32x4 acc[4][8];
#pragma unroll
  for (int i = 0; i < 4; ++i)
#pragma unroll
    for (int n = 0; n < 8; ++n) acc[i][n] = (f32x4){0.f, 0.f, 0.f, 0.f};

#pragma unroll 2
  for (int ks = 0; ks < 16; ++ks) {
    bf16x8 af[4], bfr[8];
#pragma unroll
    for (int i = 0; i < 4; ++i) {
      int row = h * 64 + i * 16 + l15;
      af[i] = *(const bf16x8*)((char*)h1s + ((row * 1024 + ks * 64 + lg * 16) ^ ((l15 & 7) << 4)));
    }
#pragma unroll
    for (int n = 0; n < 8; ++n) {
      int c = cq * 128 + n * 16 + l15;
      bfr[n] = *(const bf16x8*)(Wi2b + (size_t)c * 512 + ks * 32 + lg * 8);
    }
#pragma unroll
    for (int i = 0; i < 4; ++i)
#pragma unroll
      for (int n = 0; n < 8; ++n)
        acc[i][n] = __builtin_amdgcn_mfma_f32_16x16x32_bf16(af[i], bfr[n], acc[i][n], 0, 0, 0);
  }
  __syncthreads();   // all waves done reading h1

  // ---- h2 = relu(acc + bi2) -> h1s region (bf16, same swizzle) ----
#pragma unroll
  for (int i = 0; i < 4; ++i) {
#pragma unroll
    for (int n = 0; n < 8; ++n) {
      int c = cq * 128 + n * 16 + l15;
      float bb = bi2s[c];
#pragma unroll
      for (int r = 0; r < 4; ++r) {
        int row = h * 64 + i * 16 + 4 * lg + r;
        float v = fmaxf(acc[i][n][r] + bb, 0.f);
        *(ushort_t*)((char*)h1s + ((row * 1024 + c * 2) ^ ((row & 7) << 4))) = f2bf(v);
      }
    }
  }
  __syncthreads();

  // ---- GEMM2: logits[128][64] = h2 @ Wi3^T ; wave w owns rows [16w,16w+16) ----
  f32x4 acc2[4];
#pragma unroll
  for (int n = 0; n < 4; ++n) acc2[n] = (f32x4){0.f, 0.f, 0.f, 0.f};
#pragma unroll 4
  for (int ks = 0; ks < 16; ++ks) {
    int row = w * 16 + l15;
    bf16x8 a2 = *(const bf16x8*)((char*)h1s + ((row * 1024 + ks * 64 + lg * 16) ^ ((l15 & 7) << 4)));
#pragma unroll
    for (int n = 0; n < 4; ++n) {
      bf16x8 b2v = *(const bf16x8*)(Wi3b + (size_t)(n * 16 + l15) * 512 + ks * 32 + lg * 8);
      acc2[n] = __builtin_amdgcn_mfma_f32_16x16x32_bf16(a2, b2v, acc2[n], 0, 0, 0);
    }
  }

  // ---- epilogue: per-row softmax over 64 logits + gather-sum with a_bits ----
  {
    const float* abp = ab2 + (w >> 2) * 64;   // batch row of this wave's 16 rows
#pragma unroll
    for (int r = 0; r < 4; ++r) {
      float v[4];
      float m = -1e30f;
#pragma unroll
      for (int n = 0; n < 4; ++n) {
        v[n] = acc2[n][r] + bi3s[n * 16 + l15];
        m = fmaxf(m, v[n]);
      }
#pragma unroll
      for (int mm = 8; mm >= 1; mm >>= 1) m = fmaxf(m, __shfl_xor(m, mm));
      float s = 0.f, g = 0.f;
#pragma unroll
      for (int n = 0; n < 4; ++n) {
        float e = expf(v[n] - m);
        s += e;
        g += e * abp[n * 16 + l15];
      }
#pragma unroll
      for (int mm = 8; mm >= 1; mm >>= 1) { s += __shfl_xor(s, mm); g += __shfl_xor(g, mm); }
      if (l15 == 0) out[m0 + w * 16 + 4 * lg + r] = g / s;
    }
  }
}

extern "C" void kernel_launch(void* const* d_in, const int* in_sizes, int n_in,
                              void* d_out, int out_size, void* d_ws, size_t ws_size,
                              hipStream_t stream) {
  const float* a_bits     = (const float*)d_in[0];
  const float* shift_bits = (const float*)d_in[1];
  const float* W1  = (const float*)d_in[2];
  const float* b1  = (const float*)d_in[3];
  const float* g1  = (const float*)d_in[4];
  const float* be1 = (const float*)d_in[5];
  const float* W2  = (const float*)d_in[6];
  const float* b2  = (const float*)d_in[7];
  const float* g2  = (const float*)d_in[8];
  const float* be2 = (const float*)d_in[9];
  const float* W3  = (const float*)d_in[10];
  const float* b3  = (const float*)d_in[11];
  const float* Wi1 = (const float*)d_in[12];
  const float* bi1 = (const float*)d_in[13];
  const float* Wi2 = (const float*)d_in[14];
  const float* bi2 = (const float*)d_in[15];
  const float* Wi3 = (const float*)d_in[16];
  const float* bi3 = (const float*)d_in[17];
  float* out = (float*)d_out;

  // ws layout: sp fp32 [B][512] (8MB) | Wi2b (512KB) | Wi3b (64KB) | Wi1posT (128KB)
  //            | W2b (512KB) | W1b (64KB) | W3b (64KB) | Wi1sb (64KB)  => ~9.4MB
  float* sp = (float*)d_ws;
  ushort_t* Wi2b = (ushort_t*)((char*)d_ws + (size_t)B_N * HID * 4);
  ushort_t* Wi3b = Wi2b + 512 * 512;
  float* Wi1posT = (float*)(Wi3b + 64 * 512);
  ushort_t* W2b = (ushort_t*)(Wi1posT + 64 * 512);
  ushort_t* W1b = W2b + 512 * 512;
  ushort_t* W3b = W1b + 512 * 64;
  ushort_t* Wi1sb = W3b + 64 * 512;

  prep_kernel<<<1024, 256, 0, stream>>>(Wi2, Wi3, Wi1, W1, W2, W3,
                                        Wi2b, Wi3b, Wi1posT, W1b, W2b, W3b, Wi1sb);
  shift2_kernel<<<B_N / BT, 256, 0, stream>>>(shift_bits, W1b, b1, g1, be1,
                                              W2b, b2, g2, be2, W3b, b3, Wi1sb, bi1, sp);
  big3_kernel<<<B_N / 2, 512, 0, stream>>>(a_bits, sp, Wi1posT, Wi2b, Wi3b, bi2, bi3, out);
}

// Round 5
// 226.378 us; speedup vs baseline: 2.3599x; 2.3599x over previous
//
#include <hip/hip_runtime.h>
#include <hip/hip_bf16.h>
#include <math.h>

// Problem constants
#define B_N 4096
#define BITSN 64
#define HID 512
#define EPSV 1e-5f
#define BT 16   // batch rows per shift2 block

typedef unsigned short ushort_t;
typedef __attribute__((ext_vector_type(8))) short bf16x8;
typedef __attribute__((ext_vector_type(4))) float f32x4;

__device__ __forceinline__ ushort_t f2bf(float f) {
  unsigned u = __float_as_uint(f);
  u += 0x7FFF + ((u >> 16) & 1);   // round-to-nearest-even
  return (ushort_t)(u >> 16);
}

__device__ __forceinline__ unsigned pack2bf(float lo, float hi) {
  union { __hip_bfloat162 h; unsigned u; } cv;
  cv.h = __float22bfloat162_rn(make_float2(lo, hi));  // v_cvt_pk_bf16_f32
  return cv.u;
}

// ---------------- prep: bf16 copies, transposes, and FRAGMENT-ORDER weights ----
// Wi2f: [ks 0..15][ct 0..31][lane 0..63][8 bf16] where the fragment for
// (ks, c-tile ct) read by lane l=(lg,l15) is Wi2[ct*16+l15][ks*32+lg*8 .. +7].
// A wave's B-frag load becomes ONE linear 1KB burst (16B/lane) instead of a
// 16-cache-line scatter. Wi3f: same for Wi3: [ks2][nt 0..3][lane][8].
__global__ __launch_bounds__(256) void prep_kernel(
    const float* __restrict__ Wi2, const float* __restrict__ Wi3,
    const float* __restrict__ Wi1, const float* __restrict__ W1,
    const float* __restrict__ W2, const float* __restrict__ W3,
    float* __restrict__ Wi1posT, ushort_t* __restrict__ W1b,
    ushort_t* __restrict__ W2b, ushort_t* __restrict__ W3b,
    ushort_t* __restrict__ Wi1sb, ushort_t* __restrict__ Wi2f,
    ushort_t* __restrict__ Wi3f) {
  int idx = blockIdx.x * 256 + threadIdx.x;
  if (idx < 512 * 512) {
    W2b[idx] = f2bf(W2[idx]);
    // Wi2f frag-order scatter (dst-linear, coalesced writes)
    int j = idx & 7, lane = (idx >> 3) & 63;
    int ct = (idx >> 9) & 31, ks = idx >> 14;
    int c = ct * 16 + (lane & 15);
    int k = ks * 32 + (lane >> 4) * 8 + j;
    Wi2f[idx] = f2bf(Wi2[c * 512 + k]);
  }
  if (idx < 64 * 512) {
    W3b[idx] = f2bf(W3[idx]);
    int p = idx >> 9, i = idx & 511;
    Wi1posT[idx] = Wi1[i * 128 + p];   // pos_part[p][i] = Wi1[i][p]
    // Wi3f frag-order: idx = ((ks2*4+nt)*64+lane)*8+j
    int j = idx & 7, lane = (idx >> 3) & 63;
    int nt = (idx >> 9) & 3, ks2 = idx >> 11;
    int jr = nt * 16 + (lane & 15);
    int k = ks2 * 32 + (lane >> 4) * 8 + j;
    Wi3f[idx] = f2bf(Wi3[jr * 512 + k]);
  }
  if (idx < 512 * 64) {
    W1b[idx] = f2bf(W1[idx]);                       // [512][64]
    int j = idx >> 6, k = idx & 63;
    Wi1sb[idx] = f2bf(Wi1[j * 128 + 64 + k]);       // shift cols of Wi1: [512][64]
  }
}

// ---------------- shift decoder, MFMA-batched: 16 rows/block ----------------
__global__ __launch_bounds__(256) void shift2_kernel(
    const float* __restrict__ shift_bits,
    const ushort_t* __restrict__ W1b, const float* __restrict__ b1,
    const float* __restrict__ g1, const float* __restrict__ be1,
    const ushort_t* __restrict__ W2b, const float* __restrict__ b2,
    const float* __restrict__ g2, const float* __restrict__ be2,
    const ushort_t* __restrict__ W3b, const float* __restrict__ b3,
    const ushort_t* __restrict__ Wi1sb, const float* __restrict__ bi1,
    float* __restrict__ sp) {
  __shared__ __align__(16) ushort_t hA[BT * 512];     // 16KB: h1 (post LN1+relu)
  __shared__ __align__(16) char reg2[32 * 1024];      // phase union
  __shared__ float b1s[512], g1s[512], be1s[512];
  __shared__ float b2s[512], g2s[512], be2s[512], bi1s[512];
  __shared__ float red[4][BT][2];
  __shared__ float b3s[64];

  ushort_t* sbt = (ushort_t*)reg2;                    // phase 1: shift_bits tile [16][64]
  ushort_t* Bs  = (ushort_t*)reg2;                    // phase 2: W2 tile [512][32]
  ushort_t* h2  = (ushort_t*)reg2;                    // phase 3: h2 [16][512]
  float (*lg32)[68] = (float(*)[68])(reg2 + 16 * 1024);
  ushort_t* sb2 = (ushort_t*)(reg2 + 16 * 1024 + 16 * 68 * 4);  // soft [16][64]

  int b0 = blockIdx.x * BT;
  int t = threadIdx.x, w = t >> 6, l = t & 63, lg = l >> 4, l15 = l & 15;

  b1s[t] = b1[t];  b1s[t + 256] = b1[t + 256];
  g1s[t] = g1[t];  g1s[t + 256] = g1[t + 256];
  be1s[t] = be1[t]; be1s[t + 256] = be1[t + 256];
  b2s[t] = b2[t];  b2s[t + 256] = b2[t + 256];
  g2s[t] = g2[t];  g2s[t + 256] = g2[t + 256];
  be2s[t] = be2[t]; be2s[t + 256] = be2[t + 256];
  bi1s[t] = bi1[t]; bi1s[t + 256] = bi1[t + 256];
  if (t < 64) b3s[t] = b3[t];
  if (t < 128) {   // stage shift_bits tile -> bf16 swizzled
    int row = t >> 3, g = t & 7;
    const float* src = shift_bits + (size_t)(b0 + row) * 64 + g * 8;
    uint4 pk;
    pk.x = (unsigned)f2bf(src[0]) | ((unsigned)f2bf(src[1]) << 16);
    pk.y = (unsigned)f2bf(src[2]) | ((unsigned)f2bf(src[3]) << 16);
    pk.z = (unsigned)f2bf(src[4]) | ((unsigned)f2bf(src[5]) << 16);
    pk.w = (unsigned)f2bf(src[6]) | ((unsigned)f2bf(src[7]) << 16);
    *(uint4*)((char*)sbt + ((row * 128 + g * 16) ^ ((row & 7) << 4))) = pk;
  }
  __syncthreads();

  // ----- GEMM1: x1[16][512] = sbt @ W1^T ; wave w owns cols [w*128, w*128+128) -----
  f32x4 acc[8];
#pragma unroll
  for (int nt = 0; nt < 8; ++nt) acc[nt] = (f32x4){0.f, 0.f, 0.f, 0.f};
#pragma unroll
  for (int ks = 0; ks < 2; ++ks) {
    bf16x8 af = *(const bf16x8*)((char*)sbt + ((l15 * 128 + ks * 64 + lg * 16) ^ ((l15 & 7) << 4)));
#pragma unroll
    for (int nt = 0; nt < 8; ++nt) {
      int c = w * 128 + nt * 16 + l15;
      bf16x8 bfr = *(const bf16x8*)(W1b + (size_t)c * 64 + ks * 32 + lg * 8);
      acc[nt] = __builtin_amdgcn_mfma_f32_16x16x32_bf16(af, bfr, acc[nt], 0, 0, 0);
    }
  }
  // ----- LN1 + relu -> hA -----
  {
    float s[4] = {0.f, 0.f, 0.f, 0.f}, q[4] = {0.f, 0.f, 0.f, 0.f};
#pragma unroll
    for (int nt = 0; nt < 8; ++nt) {
      int c = w * 128 + nt * 16 + l15;
      float bb = b1s[c];
#pragma unroll
      for (int r = 0; r < 4; ++r) {
        float x = acc[nt][r] + bb;
        acc[nt][r] = x;
        s[r] += x; q[r] += x * x;
      }
    }
#pragma unroll
    for (int m = 8; m >= 1; m >>= 1)
#pragma unroll
      for (int r = 0; r < 4; ++r) { s[r] += __shfl_xor(s[r], m); q[r] += __shfl_xor(q[r], m); }
    if (l15 == 0)
#pragma unroll
      for (int r = 0; r < 4; ++r) { red[w][4 * lg + r][0] = s[r]; red[w][4 * lg + r][1] = q[r]; }
    __syncthreads();
    float mean[4], rs[4];
#pragma unroll
    for (int r = 0; r < 4; ++r) {
      int p = 4 * lg + r;
      float S = red[0][p][0] + red[1][p][0] + red[2][p][0] + red[3][p][0];
      float Q = red[0][p][1] + red[1][p][1] + red[2][p][1] + red[3][p][1];
      mean[r] = S * (1.0f / 512.0f);
      float var = Q * (1.0f / 512.0f) - mean[r] * mean[r];
      rs[r] = rsqrtf(var + EPSV);
    }
#pragma unroll
    for (int nt = 0; nt < 8; ++nt) {
      int c = w * 128 + nt * 16 + l15;
      float gg = g1s[c], bb = be1s[c];
#pragma unroll
      for (int r = 0; r < 4; ++r) {
        int p = 4 * lg + r;
        float v = (acc[nt][r] - mean[r]) * rs[r] * gg + bb;
        v = v > 0.f ? v : 0.f;
        *(ushort_t*)((char*)hA + ((p * 1024 + c * 2) ^ ((p & 7) << 4))) = f2bf(v);
      }
    }
  }
  __syncthreads();

  // ----- GEMM2: x2[16][512] = hA @ W2^T, K=512 staged in 16 chunks of 32 -----
#pragma unroll
  for (int nt = 0; nt < 8; ++nt) acc[nt] = (f32x4){0.f, 0.f, 0.f, 0.f};
  for (int step = 0; step < 16; ++step) {
    int i0 = step * 32;
#pragma unroll
    for (int qq = 0; qq < 8; ++qq) {   // stage Bs [512][32] swizzled (linear writes)
      int g = qq * 256 + t;
      int c = g >> 2, xg = g & 3;
      int ic = xg ^ ((c >> 1) & 3);
      ((uint4*)Bs)[g] = *(const uint4*)(W2b + (size_t)c * 512 + i0 + ic * 8);
    }
    __syncthreads();
    bf16x8 af = *(const bf16x8*)((char*)hA + ((l15 * 1024 + step * 64 + lg * 16) ^ ((l15 & 7) << 4)));
#pragma unroll
    for (int nt = 0; nt < 8; ++nt) {
      int c = w * 128 + nt * 16 + l15;
      bf16x8 bfr = ((const bf16x8*)Bs)[c * 4 + (lg ^ ((c >> 1) & 3))];
      acc[nt] = __builtin_amdgcn_mfma_f32_16x16x32_bf16(af, bfr, acc[nt], 0, 0, 0);
    }
    __syncthreads();
  }
  // ----- LN2 + relu -> h2 (overwrites Bs region; safe: barrier above) -----
  {
    float s[4] = {0.f, 0.f, 0.f, 0.f}, q[4] = {0.f, 0.f, 0.f, 0.f};
#pragma unroll
    for (int nt = 0; nt < 8; ++nt) {
      int c = w * 128 + nt * 16 + l15;
      float bb = b2s[c];
#pragma unroll
      for (int r = 0; r < 4; ++r) {
        float x = acc[nt][r] + bb;
        acc[nt][r] = x;
        s[r] += x; q[r] += x * x;
      }
    }
#pragma unroll
    for (int m = 8; m >= 1; m >>= 1)
#pragma unroll
      for (int r = 0; r < 4; ++r) { s[r] += __shfl_xor(s[r], m); q[r] += __shfl_xor(q[r], m); }
    if (l15 == 0)
#pragma unroll
      for (int r = 0; r < 4; ++r) { red[w][4 * lg + r][0] = s[r]; red[w][4 * lg + r][1] = q[r]; }
    __syncthreads();
    float mean[4], rs[4];
#pragma unroll
    for (int r = 0; r < 4; ++r) {
      int p = 4 * lg + r;
      float S = red[0][p][0] + red[1][p][0] + red[2][p][0] + red[3][p][0];
      float Q = red[0][p][1] + red[1][p][1] + red[2][p][1] + red[3][p][1];
      mean[r] = S * (1.0f / 512.0f);
      float var = Q * (1.0f / 512.0f) - mean[r] * mean[r];
      rs[r] = rsqrtf(var + EPSV);
    }
#pragma unroll
    for (int nt = 0; nt < 8; ++nt) {
      int c = w * 128 + nt * 16 + l15;
      float gg = g2s[c], bb = be2s[c];
#pragma unroll
      for (int r = 0; r < 4; ++r) {
        int p = 4 * lg + r;
        float v = (acc[nt][r] - mean[r]) * rs[r] * gg + bb;
        v = v > 0.f ? v : 0.f;
        *(ushort_t*)((char*)h2 + ((p * 1024 + c * 2) ^ ((p & 7) << 4))) = f2bf(v);
      }
    }
  }
  __syncthreads();

  // ----- GEMM3: logits[16][64] = h2 @ W3^T ; wave w owns cols [16w,16w+16) -----
  {
    f32x4 a3 = (f32x4){0.f, 0.f, 0.f, 0.f};
#pragma unroll
    for (int ks = 0; ks < 16; ++ks) {
      bf16x8 af = *(const bf16x8*)((char*)h2 + ((l15 * 1024 + ks * 64 + lg * 16) ^ ((l15 & 7) << 4)));
      bf16x8 bfr = *(const bf16x8*)(W3b + (size_t)(w * 16 + l15) * 512 + ks * 32 + lg * 8);
      a3 = __builtin_amdgcn_mfma_f32_16x16x32_bf16(af, bfr, a3, 0, 0, 0);
    }
    int c = w * 16 + l15;
    float bb = b3s[c];
#pragma unroll
    for (int r = 0; r < 4; ++r) lg32[4 * lg + r][c] = a3[r] + bb;
  }
  __syncthreads();

  // ----- softmax over 64 logits -> sb2 (bf16, swizzled) -----
  {
    int r = t >> 4, j = t & 15;
    float v[4];
    float m = -1e30f;
#pragma unroll
    for (int mq = 0; mq < 4; ++mq) { v[mq] = lg32[r][mq * 16 + j]; m = fmaxf(m, v[mq]); }
#pragma unroll
    for (int mk = 8; mk >= 1; mk >>= 1) m = fmaxf(m, __shfl_xor(m, mk));
    float ssum = 0.f;
#pragma unroll
    for (int mq = 0; mq < 4; ++mq) { v[mq] = expf(v[mq] - m); ssum += v[mq]; }
#pragma unroll
    for (int mk = 8; mk >= 1; mk >>= 1) ssum += __shfl_xor(ssum, mk);
    float inv = 1.f / ssum;
#pragma unroll
    for (int mq = 0; mq < 4; ++mq) {
      int c = mq * 16 + j;
      *(ushort_t*)((char*)sb2 + ((r * 128 + c * 2) ^ ((r & 7) << 4))) = f2bf(v[mq] * inv);
    }
  }
  __syncthreads();

  // ----- GEMM4: sp[16][512] = soft @ Wi1shift^T + bi1 -----
  {
    f32x4 a4[8];
#pragma unroll
    for (int nt = 0; nt < 8; ++nt) a4[nt] = (f32x4){0.f, 0.f, 0.f, 0.f};
#pragma unroll
    for (int ks = 0; ks < 2; ++ks) {
      bf16x8 af = *(const bf16x8*)((char*)sb2 + ((l15 * 128 + ks * 64 + lg * 16) ^ ((l15 & 7) << 4)));
#pragma unroll
      for (int nt = 0; nt < 8; ++nt) {
        int c = w * 128 + nt * 16 + l15;
        bf16x8 bfr = *(const bf16x8*)(Wi1sb + (size_t)c * 64 + ks * 32 + lg * 8);
        a4[nt] = __builtin_amdgcn_mfma_f32_16x16x32_bf16(af, bfr, a4[nt], 0, 0, 0);
      }
    }
#pragma unroll
    for (int nt = 0; nt < 8; ++nt) {
      int c = w * 128 + nt * 16 + l15;
      float bb = bi1s[c];
#pragma unroll
      for (int r = 0; r < 4; ++r)
        sp[(size_t)(b0 + 4 * lg + r) * 512 + c] = a4[nt][r] + bb;
    }
  }
}

// ---------------- big4: R3 structure + frag-order B + ping-pong prefetch ------
// BM=64 (1 batch row), BN=512, 8 waves. A-panel h1[64][512] in LDS once.
// B-fragments come from Wi2f in FRAGMENT ORDER: the 4 frags a wave needs at
// k-step ks are 4 linear 1KB bursts (16B/lane) -> no cache-line scatter.
// Explicit ping-pong prefetch hides L2 latency under the 16-MFMA block.
__global__ __launch_bounds__(512, 4) void big4_kernel(
    const float* __restrict__ a_bits, const float* __restrict__ sp,
    const float* __restrict__ Wi1posT,
    const ushort_t* __restrict__ Wi2f, const ushort_t* __restrict__ Wi3f,
    const float* __restrict__ bi2, const float* __restrict__ bi3,
    float* __restrict__ out) {
  __shared__ __align__(16) ushort_t h1s[64 * 512];   // 64KB, reused as h2
  __shared__ float bi2s[512];
  __shared__ float ab[64];
  __shared__ float bi3s[64];

  int b = blockIdx.x, t = threadIdx.x;
  int w = t >> 6, l = t & 63, lg = l >> 4, l15 = l & 15;

  bi2s[t] = bi2[t];
  if (t < 64) { ab[t] = a_bits[b * 64 + t]; bi3s[t] = bi3[t]; }

  // ---- phase 0: h1[64][512] = relu(sp[b] + pos) -> LDS bf16, swizzled, ONCE ----
  {
    const float* sprow = sp + (size_t)b * 512 + l * 8;
    float4 s0 = *(const float4*)(sprow);
    float4 s1 = *(const float4*)(sprow + 4);
#pragma unroll
    for (int g = 0; g < 8; ++g) {
      int p = g * 8 + w;                    // wave w covers rows {w, 8+w, ..., 56+w}
      const float4* pr = (const float4*)(Wi1posT + (size_t)p * 512 + l * 8);
      float4 p0 = pr[0], p1 = pr[1];
      float v0 = fmaxf(s0.x + p0.x, 0.f), v1 = fmaxf(s0.y + p0.y, 0.f);
      float v2 = fmaxf(s0.z + p0.z, 0.f), v3 = fmaxf(s0.w + p0.w, 0.f);
      float v4 = fmaxf(s1.x + p1.x, 0.f), v5 = fmaxf(s1.y + p1.y, 0.f);
      float v6 = fmaxf(s1.z + p1.z, 0.f), v7 = fmaxf(s1.w + p1.w, 0.f);
      uint4 pk;
      pk.x = pack2bf(v0, v1); pk.y = pack2bf(v2, v3);
      pk.z = pack2bf(v4, v5); pk.w = pack2bf(v6, v7);
      *(uint4*)((char*)h1s + ((p * 1024 + l * 16) ^ ((p & 7) << 4))) = pk;
    }
  }
  __syncthreads();

  // ---- GEMM1: h2[64][512] = h1 @ Wi2^T ; barrier-free, frag-order B, ping-pong ----
  f32x4 acc[4][4];
#pragma unroll
  for (int mt = 0; mt < 4; ++mt)
#pragma unroll
    for (int nt = 0; nt < 4; ++nt) acc[mt][nt] = (f32x4){0.f, 0.f, 0.f, 0.f};

  // wave w owns ct = 4w+nt; frag (ks, ct) lives at bf16x8 index (ks*32+ct)*64 + l
  const bf16x8* bbase = (const bf16x8*)Wi2f + ((size_t)w * 4 * 64 + l);
  bf16x8 bA[4], bB[4];
#pragma unroll
  for (int n = 0; n < 4; ++n) bA[n] = bbase[n * 64];              // ks=0

  for (int ks = 0; ks < 16; ks += 2) {
    // prefetch ks+1 into bB
#pragma unroll
    for (int n = 0; n < 4; ++n) bB[n] = bbase[(ks + 1) * 2048 + n * 64];
    {
      bf16x8 af[4];
#pragma unroll
      for (int mt = 0; mt < 4; ++mt) {
        int p = mt * 16 + l15;
        af[mt] = *(const bf16x8*)((char*)h1s + ((p * 1024 + ks * 64 + lg * 16) ^ ((l15 & 7) << 4)));
      }
#pragma unroll
      for (int mt = 0; mt < 4; ++mt)
#pragma unroll
        for (int nt = 0; nt < 4; ++nt)
          acc[mt][nt] = __builtin_amdgcn_mfma_f32_16x16x32_bf16(af[mt], bA[nt], acc[mt][nt], 0, 0, 0);
    }
    // prefetch ks+2 into bA
    if (ks < 14) {
#pragma unroll
      for (int n = 0; n < 4; ++n) bA[n] = bbase[(ks + 2) * 2048 + n * 64];
    }
    {
      bf16x8 af[4];
#pragma unroll
      for (int mt = 0; mt < 4; ++mt) {
        int p = mt * 16 + l15;
        af[mt] = *(const bf16x8*)((char*)h1s + ((p * 1024 + (ks + 1) * 64 + lg * 16) ^ ((l15 & 7) << 4)));
      }
#pragma unroll
      for (int mt = 0; mt < 4; ++mt)
#pragma unroll
        for (int nt = 0; nt < 4; ++nt)
          acc[mt][nt] = __builtin_amdgcn_mfma_f32_16x16x32_bf16(af[mt], bB[nt], acc[mt][nt], 0, 0, 0);
    }
  }
  __syncthreads();   // everyone done reading h1s

  // ---- h2 = relu(acc + bi2) -> h1s region (bf16, swizzled [p][512]) ----
#pragma unroll
  for (int mt = 0; mt < 4; ++mt) {
#pragma unroll
    for (int nt = 0; nt < 4; ++nt) {
      int c = w * 64 + nt * 16 + l15;
      float bi = bi2s[c];
#pragma unroll
      for (int r = 0; r < 4; ++r) {
        int p = mt * 16 + 4 * lg + r;
        float v = acc[mt][nt][r] + bi;
        v = v > 0.f ? v : 0.f;
        *(ushort_t*)((char*)h1s + ((p * 1024 + c * 2) ^ ((p & 7) << 4))) = f2bf(v);
      }
    }
  }
  __syncthreads();

  // ---- GEMM2 (waves 0-3): logits[64][64] = h2 @ Wi3^T, frag-order Wi3f ----
  if (w < 4) {
    f32x4 lacc[4];
#pragma unroll
    for (int n = 0; n < 4; ++n) lacc[n] = (f32x4){0.f, 0.f, 0.f, 0.f};
    int p2 = 16 * w + l15;
    const bf16x8* b3base = (const bf16x8*)Wi3f + l;
#pragma unroll 4
    for (int ks2 = 0; ks2 < 16; ++ks2) {
      bf16x8 a2 = *(const bf16x8*)((char*)h1s + ((p2 * 1024 + ks2 * 64 + lg * 16) ^ ((p2 & 7) << 4)));
#pragma unroll
      for (int nt2 = 0; nt2 < 4; ++nt2) {
        bf16x8 b2v = b3base[(ks2 * 4 + nt2) * 64];
        lacc[nt2] = __builtin_amdgcn_mfma_f32_16x16x32_bf16(a2, b2v, lacc[nt2], 0, 0, 0);
      }
    }

    // ---- epilogue: per-row softmax over 64 logits + gather-sum with a_bits ----
#pragma unroll
    for (int r = 0; r < 4; ++r) {
      float v[4];
      float m = -1e30f;
#pragma unroll
      for (int nt2 = 0; nt2 < 4; ++nt2) {
        v[nt2] = lacc[nt2][r] + bi3s[nt2 * 16 + l15];
        m = fmaxf(m, v[nt2]);
      }
#pragma unroll
      for (int mm = 8; mm >= 1; mm >>= 1) m = fmaxf(m, __shfl_xor(m, mm));
      float s = 0.f, g = 0.f;
#pragma unroll
      for (int nt2 = 0; nt2 < 4; ++nt2) {
        float e = expf(v[nt2] - m);
        s += e;
        g += e * ab[nt2 * 16 + l15];
      }
#pragma unroll
      for (int mm = 8; mm >= 1; mm >>= 1) { s += __shfl_xor(s, mm); g += __shfl_xor(g, mm); }
      if (l15 == 0) out[b * 64 + 16 * w + 4 * lg + r] = g / s;
    }
  }
}

extern "C" void kernel_launch(void* const* d_in, const int* in_sizes, int n_in,
                              void* d_out, int out_size, void* d_ws, size_t ws_size,
                              hipStream_t stream) {
  const float* a_bits     = (const float*)d_in[0];
  const float* shift_bits = (const float*)d_in[1];
  const float* W1  = (const float*)d_in[2];
  const float* b1  = (const float*)d_in[3];
  const float* g1  = (const float*)d_in[4];
  const float* be1 = (const float*)d_in[5];
  const float* W2  = (const float*)d_in[6];
  const float* b2  = (const float*)d_in[7];
  const float* g2  = (const float*)d_in[8];
  const float* be2 = (const float*)d_in[9];
  const float* W3  = (const float*)d_in[10];
  const float* b3  = (const float*)d_in[11];
  const float* Wi1 = (const float*)d_in[12];
  const float* bi1 = (const float*)d_in[13];
  const float* Wi2 = (const float*)d_in[14];
  const float* bi2 = (const float*)d_in[15];
  const float* Wi3 = (const float*)d_in[16];
  const float* bi3 = (const float*)d_in[17];
  float* out = (float*)d_out;

  // ws layout: sp fp32 [B][512] (8MB) | W2b (512KB) | W1b (64KB) | W3b (64KB)
  //            | Wi1sb (64KB) | Wi1posT fp32 (128KB) | Wi2f (512KB) | Wi3f (64KB)
  float* sp = (float*)d_ws;
  ushort_t* W2b = (ushort_t*)((char*)d_ws + (size_t)B_N * HID * 4);
  ushort_t* W1b = W2b + 512 * 512;
  ushort_t* W3b = W1b + 512 * 64;
  ushort_t* Wi1sb = W3b + 64 * 512;
  float* Wi1posT = (float*)(Wi1sb + 512 * 64);
  ushort_t* Wi2f = (ushort_t*)(Wi1posT + 64 * 512);
  ushort_t* Wi3f = Wi2f + 512 * 512;

  prep_kernel<<<1024, 256, 0, stream>>>(Wi2, Wi3, Wi1, W1, W2, W3,
                                        Wi1posT, W1b, W2b, W3b, Wi1sb, Wi2f, Wi3f);
  shift2_kernel<<<B_N / BT, 256, 0, stream>>>(shift_bits, W1b, b1, g1, be1,
                                              W2b, b2, g2, be2, W3b, b3, Wi1sb, bi1, sp);
  big4_kernel<<<B_N, 512, 0, stream>>>(a_bits, sp, Wi1posT, Wi2f, Wi3f, bi2, bi3, out);
}

// Round 6
// 214.957 us; speedup vs baseline: 2.4853x; 1.0531x over previous
//
#include <hip/hip_runtime.h>
#include <hip/hip_bf16.h>
#include <math.h>

// Problem constants
#define B_N 4096
#define BITSN 64
#define HID 512
#define EPSV 1e-5f
#define BT 16   // batch rows per shift2 block

typedef unsigned short ushort_t;
typedef __attribute__((ext_vector_type(8))) short bf16x8;
typedef __attribute__((ext_vector_type(4))) float f32x4;
typedef __attribute__((ext_vector_type(16))) float f32x16;

__device__ __forceinline__ ushort_t f2bf(float f) {
  unsigned u = __float_as_uint(f);
  u += 0x7FFF + ((u >> 16) & 1);   // round-to-nearest-even
  return (ushort_t)(u >> 16);
}

__device__ __forceinline__ unsigned pack2bf(float lo, float hi) {
  union { __hip_bfloat162 h; unsigned u; } cv;
  cv.h = __float22bfloat162_rn(make_float2(lo, hi));  // v_cvt_pk_bf16_f32
  return cv.u;
}

// ---------------- prep: bf16 copies, transposes, FRAGMENT-ORDER weights ----
// Wi2f32: 32x32x16 frag order. Frag (ks 0..31, ct 0..15) at lane l holds
//   Wi2[ct*32 + (l&31)][ks*16 + (l>>5)*8 + j], j=0..7.  idx=((ks*16+ct)*64+l)*8+j.
// Wi3f: 16x16x32 frag order for GEMM2 (unchanged from R5).
__global__ __launch_bounds__(256) void prep_kernel(
    const float* __restrict__ Wi2, const float* __restrict__ Wi3,
    const float* __restrict__ Wi1, const float* __restrict__ W1,
    const float* __restrict__ W2, const float* __restrict__ W3,
    float* __restrict__ Wi1posT, ushort_t* __restrict__ W1b,
    ushort_t* __restrict__ W2b, ushort_t* __restrict__ W3b,
    ushort_t* __restrict__ Wi1sb, ushort_t* __restrict__ Wi2f32,
    ushort_t* __restrict__ Wi3f) {
  int idx = blockIdx.x * 256 + threadIdx.x;
  if (idx < 512 * 512) {
    W2b[idx] = f2bf(W2[idx]);
    // Wi2f32 frag-order scatter (dst-linear, coalesced writes)
    int j = idx & 7, lane = (idx >> 3) & 63;
    int ct = (idx >> 9) & 15, ks = idx >> 13;
    int c = ct * 32 + (lane & 31);
    int k = ks * 16 + (lane >> 5) * 8 + j;
    Wi2f32[idx] = f2bf(Wi2[c * 512 + k]);
  }
  if (idx < 64 * 512) {
    W3b[idx] = f2bf(W3[idx]);
    int p = idx >> 9, i = idx & 511;
    Wi1posT[idx] = Wi1[i * 128 + p];   // pos_part[p][i] = Wi1[i][p]
    // Wi3f frag-order: idx = ((ks2*4+nt)*64+lane)*8+j
    int j = idx & 7, lane = (idx >> 3) & 63;
    int nt = (idx >> 9) & 3, ks2 = idx >> 11;
    int jr = nt * 16 + (lane & 15);
    int k = ks2 * 32 + (lane >> 4) * 8 + j;
    Wi3f[idx] = f2bf(Wi3[jr * 512 + k]);
  }
  if (idx < 512 * 64) {
    W1b[idx] = f2bf(W1[idx]);                       // [512][64]
    int j = idx >> 6, k = idx & 63;
    Wi1sb[idx] = f2bf(Wi1[j * 128 + 64 + k]);       // shift cols of Wi1: [512][64]
  }
}

// ---------------- shift decoder, MFMA-batched: 16 rows/block ----------------
__global__ __launch_bounds__(256) void shift2_kernel(
    const float* __restrict__ shift_bits,
    const ushort_t* __restrict__ W1b, const float* __restrict__ b1,
    const float* __restrict__ g1, const float* __restrict__ be1,
    const ushort_t* __restrict__ W2b, const float* __restrict__ b2,
    const float* __restrict__ g2, const float* __restrict__ be2,
    const ushort_t* __restrict__ W3b, const float* __restrict__ b3,
    const ushort_t* __restrict__ Wi1sb, const float* __restrict__ bi1,
    float* __restrict__ sp) {
  __shared__ __align__(16) ushort_t hA[BT * 512];     // 16KB: h1 (post LN1+relu)
  __shared__ __align__(16) char reg2[32 * 1024];      // phase union
  __shared__ float b1s[512], g1s[512], be1s[512];
  __shared__ float b2s[512], g2s[512], be2s[512], bi1s[512];
  __shared__ float red[4][BT][2];
  __shared__ float b3s[64];

  ushort_t* sbt = (ushort_t*)reg2;                    // phase 1: shift_bits tile [16][64]
  ushort_t* Bs  = (ushort_t*)reg2;                    // phase 2: W2 tile [512][32]
  ushort_t* h2  = (ushort_t*)reg2;                    // phase 3: h2 [16][512]
  float (*lg32)[68] = (float(*)[68])(reg2 + 16 * 1024);
  ushort_t* sb2 = (ushort_t*)(reg2 + 16 * 1024 + 16 * 68 * 4);  // soft [16][64]

  int b0 = blockIdx.x * BT;
  int t = threadIdx.x, w = t >> 6, l = t & 63, lg = l >> 4, l15 = l & 15;

  b1s[t] = b1[t];  b1s[t + 256] = b1[t + 256];
  g1s[t] = g1[t];  g1s[t + 256] = g1[t + 256];
  be1s[t] = be1[t]; be1s[t + 256] = be1[t + 256];
  b2s[t] = b2[t];  b2s[t + 256] = b2[t + 256];
  g2s[t] = g2[t];  g2s[t + 256] = g2[t + 256];
  be2s[t] = be2[t]; be2s[t + 256] = be2[t + 256];
  bi1s[t] = bi1[t]; bi1s[t + 256] = bi1[t + 256];
  if (t < 64) b3s[t] = b3[t];
  if (t < 128) {   // stage shift_bits tile -> bf16 swizzled
    int row = t >> 3, g = t & 7;
    const float* src = shift_bits + (size_t)(b0 + row) * 64 + g * 8;
    uint4 pk;
    pk.x = (unsigned)f2bf(src[0]) | ((unsigned)f2bf(src[1]) << 16);
    pk.y = (unsigned)f2bf(src[2]) | ((unsigned)f2bf(src[3]) << 16);
    pk.z = (unsigned)f2bf(src[4]) | ((unsigned)f2bf(src[5]) << 16);
    pk.w = (unsigned)f2bf(src[6]) | ((unsigned)f2bf(src[7]) << 16);
    *(uint4*)((char*)sbt + ((row * 128 + g * 16) ^ ((row & 7) << 4))) = pk;
  }
  __syncthreads();

  // ----- GEMM1: x1[16][512] = sbt @ W1^T ; wave w owns cols [w*128, w*128+128) -----
  f32x4 acc[8];
#pragma unroll
  for (int nt = 0; nt < 8; ++nt) acc[nt] = (f32x4){0.f, 0.f, 0.f, 0.f};
#pragma unroll
  for (int ks = 0; ks < 2; ++ks) {
    bf16x8 af = *(const bf16x8*)((char*)sbt + ((l15 * 128 + ks * 64 + lg * 16) ^ ((l15 & 7) << 4)));
#pragma unroll
    for (int nt = 0; nt < 8; ++nt) {
      int c = w * 128 + nt * 16 + l15;
      bf16x8 bfr = *(const bf16x8*)(W1b + (size_t)c * 64 + ks * 32 + lg * 8);
      acc[nt] = __builtin_amdgcn_mfma_f32_16x16x32_bf16(af, bfr, acc[nt], 0, 0, 0);
    }
  }
  // ----- LN1 + relu -> hA -----
  {
    float s[4] = {0.f, 0.f, 0.f, 0.f}, q[4] = {0.f, 0.f, 0.f, 0.f};
#pragma unroll
    for (int nt = 0; nt < 8; ++nt) {
      int c = w * 128 + nt * 16 + l15;
      float bb = b1s[c];
#pragma unroll
      for (int r = 0; r < 4; ++r) {
        float x = acc[nt][r] + bb;
        acc[nt][r] = x;
        s[r] += x; q[r] += x * x;
      }
    }
#pragma unroll
    for (int m = 8; m >= 1; m >>= 1)
#pragma unroll
      for (int r = 0; r < 4; ++r) { s[r] += __shfl_xor(s[r], m); q[r] += __shfl_xor(q[r], m); }
    if (l15 == 0)
#pragma unroll
      for (int r = 0; r < 4; ++r) { red[w][4 * lg + r][0] = s[r]; red[w][4 * lg + r][1] = q[r]; }
    __syncthreads();
    float mean[4], rs[4];
#pragma unroll
    for (int r = 0; r < 4; ++r) {
      int p = 4 * lg + r;
      float S = red[0][p][0] + red[1][p][0] + red[2][p][0] + red[3][p][0];
      float Q = red[0][p][1] + red[1][p][1] + red[2][p][1] + red[3][p][1];
      mean[r] = S * (1.0f / 512.0f);
      float var = Q * (1.0f / 512.0f) - mean[r] * mean[r];
      rs[r] = rsqrtf(var + EPSV);
    }
#pragma unroll
    for (int nt = 0; nt < 8; ++nt) {
      int c = w * 128 + nt * 16 + l15;
      float gg = g1s[c], bb = be1s[c];
#pragma unroll
      for (int r = 0; r < 4; ++r) {
        int p = 4 * lg + r;
        float v = (acc[nt][r] - mean[r]) * rs[r] * gg + bb;
        v = v > 0.f ? v : 0.f;
        *(ushort_t*)((char*)hA + ((p * 1024 + c * 2) ^ ((p & 7) << 4))) = f2bf(v);
      }
    }
  }
  __syncthreads();

  // ----- GEMM2: x2[16][512] = hA @ W2^T, K=512 staged in 16 chunks of 32 -----
#pragma unroll
  for (int nt = 0; nt < 8; ++nt) acc[nt] = (f32x4){0.f, 0.f, 0.f, 0.f};
  for (int step = 0; step < 16; ++step) {
    int i0 = step * 32;
#pragma unroll
    for (int qq = 0; qq < 8; ++qq) {   // stage Bs [512][32] swizzled (linear writes)
      int g = qq * 256 + t;
      int c = g >> 2, xg = g & 3;
      int ic = xg ^ ((c >> 1) & 3);
      ((uint4*)Bs)[g] = *(const uint4*)(W2b + (size_t)c * 512 + i0 + ic * 8);
    }
    __syncthreads();
    bf16x8 af = *(const bf16x8*)((char*)hA + ((l15 * 1024 + step * 64 + lg * 16) ^ ((l15 & 7) << 4)));
#pragma unroll
    for (int nt = 0; nt < 8; ++nt) {
      int c = w * 128 + nt * 16 + l15;
      bf16x8 bfr = ((const bf16x8*)Bs)[c * 4 + (lg ^ ((c >> 1) & 3))];
      acc[nt] = __builtin_amdgcn_mfma_f32_16x16x32_bf16(af, bfr, acc[nt], 0, 0, 0);
    }
    __syncthreads();
  }
  // ----- LN2 + relu -> h2 (overwrites Bs region; safe: barrier above) -----
  {
    float s[4] = {0.f, 0.f, 0.f, 0.f}, q[4] = {0.f, 0.f, 0.f, 0.f};
#pragma unroll
    for (int nt = 0; nt < 8; ++nt) {
      int c = w * 128 + nt * 16 + l15;
      float bb = b2s[c];
#pragma unroll
      for (int r = 0; r < 4; ++r) {
        float x = acc[nt][r] + bb;
        acc[nt][r] = x;
        s[r] += x; q[r] += x * x;
      }
    }
#pragma unroll
    for (int m = 8; m >= 1; m >>= 1)
#pragma unroll
      for (int r = 0; r < 4; ++r) { s[r] += __shfl_xor(s[r], m); q[r] += __shfl_xor(q[r], m); }
    if (l15 == 0)
#pragma unroll
      for (int r = 0; r < 4; ++r) { red[w][4 * lg + r][0] = s[r]; red[w][4 * lg + r][1] = q[r]; }
    __syncthreads();
    float mean[4], rs[4];
#pragma unroll
    for (int r = 0; r < 4; ++r) {
      int p = 4 * lg + r;
      float S = red[0][p][0] + red[1][p][0] + red[2][p][0] + red[3][p][0];
      float Q = red[0][p][1] + red[1][p][1] + red[2][p][1] + red[3][p][1];
      mean[r] = S * (1.0f / 512.0f);
      float var = Q * (1.0f / 512.0f) - mean[r] * mean[r];
      rs[r] = rsqrtf(var + EPSV);
    }
#pragma unroll
    for (int nt = 0; nt < 8; ++nt) {
      int c = w * 128 + nt * 16 + l15;
      float gg = g2s[c], bb = be2s[c];
#pragma unroll
      for (int r = 0; r < 4; ++r) {
        int p = 4 * lg + r;
        float v = (acc[nt][r] - mean[r]) * rs[r] * gg + bb;
        v = v > 0.f ? v : 0.f;
        *(ushort_t*)((char*)h2 + ((p * 1024 + c * 2) ^ ((p & 7) << 4))) = f2bf(v);
      }
    }
  }
  __syncthreads();

  // ----- GEMM3: logits[16][64] = h2 @ W3^T ; wave w owns cols [16w,16w+16) -----
  {
    f32x4 a3 = (f32x4){0.f, 0.f, 0.f, 0.f};
#pragma unroll
    for (int ks = 0; ks < 16; ++ks) {
      bf16x8 af = *(const bf16x8*)((char*)h2 + ((l15 * 1024 + ks * 64 + lg * 16) ^ ((l15 & 7) << 4)));
      bf16x8 bfr = *(const bf16x8*)(W3b + (size_t)(w * 16 + l15) * 512 + ks * 32 + lg * 8);
      a3 = __builtin_amdgcn_mfma_f32_16x16x32_bf16(af, bfr, a3, 0, 0, 0);
    }
    int c = w * 16 + l15;
    float bb = b3s[c];
#pragma unroll
    for (int r = 0; r < 4; ++r) lg32[4 * lg + r][c] = a3[r] + bb;
  }
  __syncthreads();

  // ----- softmax over 64 logits -> sb2 (bf16, swizzled) -----
  {
    int r = t >> 4, j = t & 15;
    float v[4];
    float m = -1e30f;
#pragma unroll
    for (int mq = 0; mq < 4; ++mq) { v[mq] = lg32[r][mq * 16 + j]; m = fmaxf(m, v[mq]); }
#pragma unroll
    for (int mk = 8; mk >= 1; mk >>= 1) m = fmaxf(m, __shfl_xor(m, mk));
    float ssum = 0.f;
#pragma unroll
    for (int mq = 0; mq < 4; ++mq) { v[mq] = expf(v[mq] - m); ssum += v[mq]; }
#pragma unroll
    for (int mk = 8; mk >= 1; mk >>= 1) ssum += __shfl_xor(ssum, mk);
    float inv = 1.f / ssum;
#pragma unroll
    for (int mq = 0; mq < 4; ++mq) {
      int c = mq * 16 + j;
      *(ushort_t*)((char*)sb2 + ((r * 128 + c * 2) ^ ((r & 7) << 4))) = f2bf(v[mq] * inv);
    }
  }
  __syncthreads();

  // ----- GEMM4: sp[16][512] = soft @ Wi1shift^T + bi1 -----
  {
    f32x4 a4[8];
#pragma unroll
    for (int nt = 0; nt < 8; ++nt) a4[nt] = (f32x4){0.f, 0.f, 0.f, 0.f};
#pragma unroll
    for (int ks = 0; ks < 2; ++ks) {
      bf16x8 af = *(const bf16x8*)((char*)sb2 + ((l15 * 128 + ks * 64 + lg * 16) ^ ((l15 & 7) << 4)));
#pragma unroll
      for (int nt = 0; nt < 8; ++nt) {
        int c = w * 128 + nt * 16 + l15;
        bf16x8 bfr = *(const bf16x8*)(Wi1sb + (size_t)c * 64 + ks * 32 + lg * 8);
        a4[nt] = __builtin_amdgcn_mfma_f32_16x16x32_bf16(af, bfr, a4[nt], 0, 0, 0);
      }
    }
#pragma unroll
    for (int nt = 0; nt < 8; ++nt) {
      int c = w * 128 + nt * 16 + l15;
      float bb = bi1s[c];
#pragma unroll
      for (int r = 0; r < 4; ++r)
        sp[(size_t)(b0 + 4 * lg + r) * 512 + c] = a4[nt][r] + bb;
    }
  }
}

// ---------------- big5: 32x32x16 GEMM1 + &15 swizzle + frag-order B + ping-pong ----
// BM=64 (1 batch row), BN=512, 8 waves. A-panel h1[64][512] in LDS once
// (swizzle: byte ^= (row&15)<<4). Wave w owns cols [64w,64w+64) = ct {2w,2w+1}.
// GEMM1: 32 k-steps of 16; per step 2 A ds_read_b128 + 2 B 1KB-burst loads +
// 4 mfma_32x32x16. C/D layout (HW-verified): col=lane&31, row=(reg&3)+8*(reg>>2)+4*(lane>>5).
__global__ __launch_bounds__(512, 4) void big5_kernel(
    const float* __restrict__ a_bits, const float* __restrict__ sp,
    const float* __restrict__ Wi1posT,
    const ushort_t* __restrict__ Wi2f32, const ushort_t* __restrict__ Wi3f,
    const float* __restrict__ bi2, const float* __restrict__ bi3,
    float* __restrict__ out) {
  __shared__ __align__(16) ushort_t h1s[64 * 512];   // 64KB, reused as h2
  __shared__ float bi2s[512];
  __shared__ float ab[64];
  __shared__ float bi3s[64];

  int b = blockIdx.x, t = threadIdx.x;
  int w = t >> 6, l = t & 63, lg = l >> 4, l15 = l & 15;
  int l31 = l & 31, hi = l >> 5;

  bi2s[t] = bi2[t];
  if (t < 64) { ab[t] = a_bits[b * 64 + t]; bi3s[t] = bi3[t]; }

  // ---- phase 0: h1[64][512] = relu(sp[b] + pos) -> LDS bf16, swizzled, ONCE ----
  {
    const float* sprow = sp + (size_t)b * 512 + l * 8;
    float4 s0 = *(const float4*)(sprow);
    float4 s1 = *(const float4*)(sprow + 4);
#pragma unroll
    for (int g = 0; g < 8; ++g) {
      int p = g * 8 + w;                    // wave w covers rows {w, 8+w, ..., 56+w}
      const float4* pr = (const float4*)(Wi1posT + (size_t)p * 512 + l * 8);
      float4 p0 = pr[0], p1 = pr[1];
      float v0 = fmaxf(s0.x + p0.x, 0.f), v1 = fmaxf(s0.y + p0.y, 0.f);
      float v2 = fmaxf(s0.z + p0.z, 0.f), v3 = fmaxf(s0.w + p0.w, 0.f);
      float v4 = fmaxf(s1.x + p1.x, 0.f), v5 = fmaxf(s1.y + p1.y, 0.f);
      float v6 = fmaxf(s1.z + p1.z, 0.f), v7 = fmaxf(s1.w + p1.w, 0.f);
      uint4 pk;
      pk.x = pack2bf(v0, v1); pk.y = pack2bf(v2, v3);
      pk.z = pack2bf(v4, v5); pk.w = pack2bf(v6, v7);
      *(uint4*)((char*)h1s + ((p * 1024 + l * 16) ^ ((p & 15) << 4))) = pk;
    }
  }
  __syncthreads();

  // ---- GEMM1: h2[64][512] = h1 @ Wi2^T ; 32x32x16, barrier-free, ping-pong B ----
  f32x16 acc[2][2];
#pragma unroll
  for (int mt = 0; mt < 2; ++mt)
#pragma unroll
    for (int nt = 0; nt < 2; ++nt)
#pragma unroll
      for (int r = 0; r < 16; ++r) acc[mt][nt][r] = 0.f;

  // frag (ks, ct) at bf16x8 index (ks*16+ct)*64 + l ; wave w: ct0 = 2w
  const bf16x8* bbase = (const bf16x8*)Wi2f32 + ((size_t)(2 * w) * 64 + l);
  bf16x8 bA[2], bB[2];
#pragma unroll
  for (int n = 0; n < 2; ++n) bA[n] = bbase[n * 64];              // ks=0

  for (int ks = 0; ks < 32; ks += 2) {
    // prefetch ks+1 into bB
#pragma unroll
    for (int n = 0; n < 2; ++n) bB[n] = bbase[(size_t)(ks + 1) * 1024 + n * 64];
    {
      bf16x8 af[2];
#pragma unroll
      for (int mt = 0; mt < 2; ++mt) {
        int row = mt * 32 + l31;
        af[mt] = *(const bf16x8*)((char*)h1s + ((row * 1024 + ks * 32 + hi * 16) ^ ((row & 15) << 4)));
      }
#pragma unroll
      for (int mt = 0; mt < 2; ++mt)
#pragma unroll
        for (int nt = 0; nt < 2; ++nt)
          acc[mt][nt] = __builtin_amdgcn_mfma_f32_32x32x16_bf16(af[mt], bA[nt], acc[mt][nt], 0, 0, 0);
    }
    // prefetch ks+2 into bA
    if (ks < 30) {
#pragma unroll
      for (int n = 0; n < 2; ++n) bA[n] = bbase[(size_t)(ks + 2) * 1024 + n * 64];
    }
    {
      bf16x8 af[2];
#pragma unroll
      for (int mt = 0; mt < 2; ++mt) {
        int row = mt * 32 + l31;
        af[mt] = *(const bf16x8*)((char*)h1s + ((row * 1024 + (ks + 1) * 32 + hi * 16) ^ ((row & 15) << 4)));
      }
#pragma unroll
      for (int mt = 0; mt < 2; ++mt)
#pragma unroll
        for (int nt = 0; nt < 2; ++nt)
          acc[mt][nt] = __builtin_amdgcn_mfma_f32_32x32x16_bf16(af[mt], bB[nt], acc[mt][nt], 0, 0, 0);
    }
  }
  __syncthreads();   // everyone done reading h1s

  // ---- h2 = relu(acc + bi2) -> h1s region (bf16, &15 swizzle) ----
  // C/D: col = nt*32 + l31 (+w*64), row = mt*32 + (r&3) + 8*(r>>2) + 4*hi
#pragma unroll
  for (int mt = 0; mt < 2; ++mt) {
#pragma unroll
    for (int nt = 0; nt < 2; ++nt) {
      int c = w * 64 + nt * 32 + l31;
      float bi = bi2s[c];
#pragma unroll
      for (int r = 0; r < 16; ++r) {
        int row = mt * 32 + (r & 3) + 8 * (r >> 2) + 4 * hi;
        float v = acc[mt][nt][r] + bi;
        v = v > 0.f ? v : 0.f;
        *(ushort_t*)((char*)h1s + ((row * 1024 + c * 2) ^ ((row & 15) << 4))) = f2bf(v);
      }
    }
  }
  __syncthreads();

  // ---- GEMM2 (waves 0-3): logits[64][64] = h2 @ Wi3^T, frag-order Wi3f (16x16) ----
  if (w < 4) {
    f32x4 lacc[4];
#pragma unroll
    for (int n = 0; n < 4; ++n) lacc[n] = (f32x4){0.f, 0.f, 0.f, 0.f};
    int p2 = 16 * w + l15;
    const bf16x8* b3base = (const bf16x8*)Wi3f + l;
#pragma unroll 4
    for (int ks2 = 0; ks2 < 16; ++ks2) {
      bf16x8 a2 = *(const bf16x8*)((char*)h1s + ((p2 * 1024 + ks2 * 64 + lg * 16) ^ ((p2 & 15) << 4)));
#pragma unroll
      for (int nt2 = 0; nt2 < 4; ++nt2) {
        bf16x8 b2v = b3base[(ks2 * 4 + nt2) * 64];
        lacc[nt2] = __builtin_amdgcn_mfma_f32_16x16x32_bf16(a2, b2v, lacc[nt2], 0, 0, 0);
      }
    }

    // ---- epilogue: per-row softmax over 64 logits + gather-sum with a_bits ----
#pragma unroll
    for (int r = 0; r < 4; ++r) {
      float v[4];
      float m = -1e30f;
#pragma unroll
      for (int nt2 = 0; nt2 < 4; ++nt2) {
        v[nt2] = lacc[nt2][r] + bi3s[nt2 * 16 + l15];
        m = fmaxf(m, v[nt2]);
      }
#pragma unroll
      for (int mm = 8; mm >= 1; mm >>= 1) m = fmaxf(m, __shfl_xor(m, mm));
      float s = 0.f, g = 0.f;
#pragma unroll
      for (int nt2 = 0; nt2 < 4; ++nt2) {
        float e = expf(v[nt2] - m);
        s += e;
        g += e * ab[nt2 * 16 + l15];
      }
#pragma unroll
      for (int mm = 8; mm >= 1; mm >>= 1) { s += __shfl_xor(s, mm); g += __shfl_xor(g, mm); }
      if (l15 == 0) out[b * 64 + 16 * w + 4 * lg + r] = g / s;
    }
  }
}

extern "C" void kernel_launch(void* const* d_in, const int* in_sizes, int n_in,
                              void* d_out, int out_size, void* d_ws, size_t ws_size,
                              hipStream_t stream) {
  const float* a_bits     = (const float*)d_in[0];
  const float* shift_bits = (const float*)d_in[1];
  const float* W1  = (const float*)d_in[2];
  const float* b1  = (const float*)d_in[3];
  const float* g1  = (const float*)d_in[4];
  const float* be1 = (const float*)d_in[5];
  const float* W2  = (const float*)d_in[6];
  const float* b2  = (const float*)d_in[7];
  const float* g2  = (const float*)d_in[8];
  const float* be2 = (const float*)d_in[9];
  const float* W3  = (const float*)d_in[10];
  const float* b3  = (const float*)d_in[11];
  const float* Wi1 = (const float*)d_in[12];
  const float* bi1 = (const float*)d_in[13];
  const float* Wi2 = (const float*)d_in[14];
  const float* bi2 = (const float*)d_in[15];
  const float* Wi3 = (const float*)d_in[16];
  const float* bi3 = (const float*)d_in[17];
  float* out = (float*)d_out;

  // ws layout: sp fp32 [B][512] (8MB) | W2b (512KB) | W1b (64KB) | W3b (64KB)
  //            | Wi1sb (64KB) | Wi1posT fp32 (128KB) | Wi2f32 (512KB) | Wi3f (64KB)
  float* sp = (float*)d_ws;
  ushort_t* W2b = (ushort_t*)((char*)d_ws + (size_t)B_N * HID * 4);
  ushort_t* W1b = W2b + 512 * 512;
  ushort_t* W3b = W1b + 512 * 64;
  ushort_t* Wi1sb = W3b + 64 * 512;
  float* Wi1posT = (float*)(Wi1sb + 512 * 64);
  ushort_t* Wi2f32 = (ushort_t*)(Wi1posT + 64 * 512);
  ushort_t* Wi3f = Wi2f32 + 512 * 512;

  prep_kernel<<<1024, 256, 0, stream>>>(Wi2, Wi3, Wi1, W1, W2, W3,
                                        Wi1posT, W1b, W2b, W3b, Wi1sb, Wi2f32, Wi3f);
  shift2_kernel<<<B_N / BT, 256, 0, stream>>>(shift_bits, W1b, b1, g1, be1,
                                              W2b, b2, g2, be2, W3b, b3, Wi1sb, bi1, sp);
  big5_kernel<<<B_N, 512, 0, stream>>>(a_bits, sp, Wi1posT, Wi2f32, Wi3f, bi2, bi3, out);
}

// Round 7
// 213.136 us; speedup vs baseline: 2.5065x; 1.0085x over previous
//
#include <hip/hip_runtime.h>
#include <hip/hip_bf16.h>
#include <math.h>

// Problem constants
#define B_N 4096
#define BITSN 64
#define HID 512
#define EPSV 1e-5f
#define BT 16   // batch rows per shift2 block

typedef unsigned short ushort_t;
typedef __attribute__((ext_vector_type(8))) short bf16x8;
typedef __attribute__((ext_vector_type(4))) float f32x4;
typedef __attribute__((ext_vector_type(16))) float f32x16;

__device__ __forceinline__ ushort_t f2bf(float f) {
  unsigned u = __float_as_uint(f);
  u += 0x7FFF + ((u >> 16) & 1);   // round-to-nearest-even
  return (ushort_t)(u >> 16);
}

__device__ __forceinline__ unsigned pack2bf(float lo, float hi) {
  union { __hip_bfloat162 h; unsigned u; } cv;
  cv.h = __float22bfloat162_rn(make_float2(lo, hi));  // v_cvt_pk_bf16_f32
  return cv.u;
}

// ---------------- prep: bf16 copies, transposes, FRAGMENT-ORDER weights ----
// Wi2f32: 32x32x16 frag order. Frag (ks 0..31, ct 0..15) at lane l holds
//   Wi2[ct*32 + (l&31)][ks*16 + (l>>5)*8 + j], j=0..7.  idx=((ks*16+ct)*64+l)*8+j.
// Wi3f: 16x16x32 frag order for GEMM2.
__global__ __launch_bounds__(256) void prep_kernel(
    const float* __restrict__ Wi2, const float* __restrict__ Wi3,
    const float* __restrict__ Wi1, const float* __restrict__ W1,
    const float* __restrict__ W2, const float* __restrict__ W3,
    float* __restrict__ Wi1posT, ushort_t* __restrict__ W1b,
    ushort_t* __restrict__ W2b, ushort_t* __restrict__ W3b,
    ushort_t* __restrict__ Wi1sb, ushort_t* __restrict__ Wi2f32,
    ushort_t* __restrict__ Wi3f) {
  int idx = blockIdx.x * 256 + threadIdx.x;
  if (idx < 512 * 512) {
    W2b[idx] = f2bf(W2[idx]);
    // Wi2f32 frag-order scatter (dst-linear, coalesced writes)
    int j = idx & 7, lane = (idx >> 3) & 63;
    int ct = (idx >> 9) & 15, ks = idx >> 13;
    int c = ct * 32 + (lane & 31);
    int k = ks * 16 + (lane >> 5) * 8 + j;
    Wi2f32[idx] = f2bf(Wi2[c * 512 + k]);
  }
  if (idx < 64 * 512) {
    W3b[idx] = f2bf(W3[idx]);
    int p = idx >> 9, i = idx & 511;
    Wi1posT[idx] = Wi1[i * 128 + p];   // pos_part[p][i] = Wi1[i][p]
    // Wi3f frag-order: idx = ((ks2*4+nt)*64+lane)*8+j
    int j = idx & 7, lane = (idx >> 3) & 63;
    int nt = (idx >> 9) & 3, ks2 = idx >> 11;
    int jr = nt * 16 + (lane & 15);
    int k = ks2 * 32 + (lane >> 4) * 8 + j;
    Wi3f[idx] = f2bf(Wi3[jr * 512 + k]);
  }
  if (idx < 512 * 64) {
    W1b[idx] = f2bf(W1[idx]);                       // [512][64]
    int j = idx >> 6, k = idx & 63;
    Wi1sb[idx] = f2bf(Wi1[j * 128 + 64 + k]);       // shift cols of Wi1: [512][64]
  }
}

// ---------------- shift decoder, MFMA-batched: 16 rows/block ----------------
__global__ __launch_bounds__(256) void shift2_kernel(
    const float* __restrict__ shift_bits,
    const ushort_t* __restrict__ W1b, const float* __restrict__ b1,
    const float* __restrict__ g1, const float* __restrict__ be1,
    const ushort_t* __restrict__ W2b, const float* __restrict__ b2,
    const float* __restrict__ g2, const float* __restrict__ be2,
    const ushort_t* __restrict__ W3b, const float* __restrict__ b3,
    const ushort_t* __restrict__ Wi1sb, const float* __restrict__ bi1,
    float* __restrict__ sp) {
  __shared__ __align__(16) ushort_t hA[BT * 512];     // 16KB: h1 (post LN1+relu)
  __shared__ __align__(16) char reg2[32 * 1024];      // phase union
  __shared__ float b1s[512], g1s[512], be1s[512];
  __shared__ float b2s[512], g2s[512], be2s[512], bi1s[512];
  __shared__ float red[4][BT][2];
  __shared__ float b3s[64];

  ushort_t* sbt = (ushort_t*)reg2;                    // phase 1: shift_bits tile [16][64]
  ushort_t* Bs  = (ushort_t*)reg2;                    // phase 2: W2 tile [512][32]
  ushort_t* h2  = (ushort_t*)reg2;                    // phase 3: h2 [16][512]
  float (*lg32)[68] = (float(*)[68])(reg2 + 16 * 1024);
  ushort_t* sb2 = (ushort_t*)(reg2 + 16 * 1024 + 16 * 68 * 4);  // soft [16][64]

  int b0 = blockIdx.x * BT;
  int t = threadIdx.x, w = t >> 6, l = t & 63, lg = l >> 4, l15 = l & 15;

  b1s[t] = b1[t];  b1s[t + 256] = b1[t + 256];
  g1s[t] = g1[t];  g1s[t + 256] = g1[t + 256];
  be1s[t] = be1[t]; be1s[t + 256] = be1[t + 256];
  b2s[t] = b2[t];  b2s[t + 256] = b2[t + 256];
  g2s[t] = g2[t];  g2s[t + 256] = g2[t + 256];
  be2s[t] = be2[t]; be2s[t + 256] = be2[t + 256];
  bi1s[t] = bi1[t]; bi1s[t + 256] = bi1[t + 256];
  if (t < 64) b3s[t] = b3[t];
  if (t < 128) {   // stage shift_bits tile -> bf16 swizzled
    int row = t >> 3, g = t & 7;
    const float* src = shift_bits + (size_t)(b0 + row) * 64 + g * 8;
    uint4 pk;
    pk.x = (unsigned)f2bf(src[0]) | ((unsigned)f2bf(src[1]) << 16);
    pk.y = (unsigned)f2bf(src[2]) | ((unsigned)f2bf(src[3]) << 16);
    pk.z = (unsigned)f2bf(src[4]) | ((unsigned)f2bf(src[5]) << 16);
    pk.w = (unsigned)f2bf(src[6]) | ((unsigned)f2bf(src[7]) << 16);
    *(uint4*)((char*)sbt + ((row * 128 + g * 16) ^ ((row & 7) << 4))) = pk;
  }
  __syncthreads();

  // ----- GEMM1: x1[16][512] = sbt @ W1^T ; wave w owns cols [w*128, w*128+128) -----
  f32x4 acc[8];
#pragma unroll
  for (int nt = 0; nt < 8; ++nt) acc[nt] = (f32x4){0.f, 0.f, 0.f, 0.f};
#pragma unroll
  for (int ks = 0; ks < 2; ++ks) {
    bf16x8 af = *(const bf16x8*)((char*)sbt + ((l15 * 128 + ks * 64 + lg * 16) ^ ((l15 & 7) << 4)));
#pragma unroll
    for (int nt = 0; nt < 8; ++nt) {
      int c = w * 128 + nt * 16 + l15;
      bf16x8 bfr = *(const bf16x8*)(W1b + (size_t)c * 64 + ks * 32 + lg * 8);
      acc[nt] = __builtin_amdgcn_mfma_f32_16x16x32_bf16(af, bfr, acc[nt], 0, 0, 0);
    }
  }
  // ----- LN1 + relu -> hA -----
  {
    float s[4] = {0.f, 0.f, 0.f, 0.f}, q[4] = {0.f, 0.f, 0.f, 0.f};
#pragma unroll
    for (int nt = 0; nt < 8; ++nt) {
      int c = w * 128 + nt * 16 + l15;
      float bb = b1s[c];
#pragma unroll
      for (int r = 0; r < 4; ++r) {
        float x = acc[nt][r] + bb;
        acc[nt][r] = x;
        s[r] += x; q[r] += x * x;
      }
    }
#pragma unroll
    for (int m = 8; m >= 1; m >>= 1)
#pragma unroll
      for (int r = 0; r < 4; ++r) { s[r] += __shfl_xor(s[r], m); q[r] += __shfl_xor(q[r], m); }
    if (l15 == 0)
#pragma unroll
      for (int r = 0; r < 4; ++r) { red[w][4 * lg + r][0] = s[r]; red[w][4 * lg + r][1] = q[r]; }
    __syncthreads();
    float mean[4], rs[4];
#pragma unroll
    for (int r = 0; r < 4; ++r) {
      int p = 4 * lg + r;
      float S = red[0][p][0] + red[1][p][0] + red[2][p][0] + red[3][p][0];
      float Q = red[0][p][1] + red[1][p][1] + red[2][p][1] + red[3][p][1];
      mean[r] = S * (1.0f / 512.0f);
      float var = Q * (1.0f / 512.0f) - mean[r] * mean[r];
      rs[r] = rsqrtf(var + EPSV);
    }
#pragma unroll
    for (int nt = 0; nt < 8; ++nt) {
      int c = w * 128 + nt * 16 + l15;
      float gg = g1s[c], bb = be1s[c];
#pragma unroll
      for (int r = 0; r < 4; ++r) {
        int p = 4 * lg + r;
        float v = (acc[nt][r] - mean[r]) * rs[r] * gg + bb;
        v = v > 0.f ? v : 0.f;
        *(ushort_t*)((char*)hA + ((p * 1024 + c * 2) ^ ((p & 7) << 4))) = f2bf(v);
      }
    }
  }
  __syncthreads();

  // ----- GEMM2: x2[16][512] = hA @ W2^T, K=512 staged in 16 chunks of 32 -----
#pragma unroll
  for (int nt = 0; nt < 8; ++nt) acc[nt] = (f32x4){0.f, 0.f, 0.f, 0.f};
  for (int step = 0; step < 16; ++step) {
    int i0 = step * 32;
#pragma unroll
    for (int qq = 0; qq < 8; ++qq) {   // stage Bs [512][32] swizzled (linear writes)
      int g = qq * 256 + t;
      int c = g >> 2, xg = g & 3;
      int ic = xg ^ ((c >> 1) & 3);
      ((uint4*)Bs)[g] = *(const uint4*)(W2b + (size_t)c * 512 + i0 + ic * 8);
    }
    __syncthreads();
    bf16x8 af = *(const bf16x8*)((char*)hA + ((l15 * 1024 + step * 64 + lg * 16) ^ ((l15 & 7) << 4)));
#pragma unroll
    for (int nt = 0; nt < 8; ++nt) {
      int c = w * 128 + nt * 16 + l15;
      bf16x8 bfr = ((const bf16x8*)Bs)[c * 4 + (lg ^ ((c >> 1) & 3))];
      acc[nt] = __builtin_amdgcn_mfma_f32_16x16x32_bf16(af, bfr, acc[nt], 0, 0, 0);
    }
    __syncthreads();
  }
  // ----- LN2 + relu -> h2 (overwrites Bs region; safe: barrier above) -----
  {
    float s[4] = {0.f, 0.f, 0.f, 0.f}, q[4] = {0.f, 0.f, 0.f, 0.f};
#pragma unroll
    for (int nt = 0; nt < 8; ++nt) {
      int c = w * 128 + nt * 16 + l15;
      float bb = b2s[c];
#pragma unroll
      for (int r = 0; r < 4; ++r) {
        float x = acc[nt][r] + bb;
        acc[nt][r] = x;
        s[r] += x; q[r] += x * x;
      }
    }
#pragma unroll
    for (int m = 8; m >= 1; m >>= 1)
#pragma unroll
      for (int r = 0; r < 4; ++r) { s[r] += __shfl_xor(s[r], m); q[r] += __shfl_xor(q[r], m); }
    if (l15 == 0)
#pragma unroll
      for (int r = 0; r < 4; ++r) { red[w][4 * lg + r][0] = s[r]; red[w][4 * lg + r][1] = q[r]; }
    __syncthreads();
    float mean[4], rs[4];
#pragma unroll
    for (int r = 0; r < 4; ++r) {
      int p = 4 * lg + r;
      float S = red[0][p][0] + red[1][p][0] + red[2][p][0] + red[3][p][0];
      float Q = red[0][p][1] + red[1][p][1] + red[2][p][1] + red[3][p][1];
      mean[r] = S * (1.0f / 512.0f);
      float var = Q * (1.0f / 512.0f) - mean[r] * mean[r];
      rs[r] = rsqrtf(var + EPSV);
    }
#pragma unroll
    for (int nt = 0; nt < 8; ++nt) {
      int c = w * 128 + nt * 16 + l15;
      float gg = g2s[c], bb = be2s[c];
#pragma unroll
      for (int r = 0; r < 4; ++r) {
        int p = 4 * lg + r;
        float v = (acc[nt][r] - mean[r]) * rs[r] * gg + bb;
        v = v > 0.f ? v : 0.f;
        *(ushort_t*)((char*)h2 + ((p * 1024 + c * 2) ^ ((p & 7) << 4))) = f2bf(v);
      }
    }
  }
  __syncthreads();

  // ----- GEMM3: logits[16][64] = h2 @ W3^T ; wave w owns cols [16w,16w+16) -----
  {
    f32x4 a3 = (f32x4){0.f, 0.f, 0.f, 0.f};
#pragma unroll
    for (int ks = 0; ks < 16; ++ks) {
      bf16x8 af = *(const bf16x8*)((char*)h2 + ((l15 * 1024 + ks * 64 + lg * 16) ^ ((l15 & 7) << 4)));
      bf16x8 bfr = *(const bf16x8*)(W3b + (size_t)(w * 16 + l15) * 512 + ks * 32 + lg * 8);
      a3 = __builtin_amdgcn_mfma_f32_16x16x32_bf16(af, bfr, a3, 0, 0, 0);
    }
    int c = w * 16 + l15;
    float bb = b3s[c];
#pragma unroll
    for (int r = 0; r < 4; ++r) lg32[4 * lg + r][c] = a3[r] + bb;
  }
  __syncthreads();

  // ----- softmax over 64 logits -> sb2 (bf16, swizzled) -----
  {
    int r = t >> 4, j = t & 15;
    float v[4];
    float m = -1e30f;
#pragma unroll
    for (int mq = 0; mq < 4; ++mq) { v[mq] = lg32[r][mq * 16 + j]; m = fmaxf(m, v[mq]); }
#pragma unroll
    for (int mk = 8; mk >= 1; mk >>= 1) m = fmaxf(m, __shfl_xor(m, mk));
    float ssum = 0.f;
#pragma unroll
    for (int mq = 0; mq < 4; ++mq) { v[mq] = expf(v[mq] - m); ssum += v[mq]; }
#pragma unroll
    for (int mk = 8; mk >= 1; mk >>= 1) ssum += __shfl_xor(ssum, mk);
    float inv = 1.f / ssum;
#pragma unroll
    for (int mq = 0; mq < 4; ++mq) {
      int c = mq * 16 + j;
      *(ushort_t*)((char*)sb2 + ((r * 128 + c * 2) ^ ((r & 7) << 4))) = f2bf(v[mq] * inv);
    }
  }
  __syncthreads();

  // ----- GEMM4: sp[16][512] = soft @ Wi1shift^T + bi1 -----
  {
    f32x4 a4[8];
#pragma unroll
    for (int nt = 0; nt < 8; ++nt) a4[nt] = (f32x4){0.f, 0.f, 0.f, 0.f};
#pragma unroll
    for (int ks = 0; ks < 2; ++ks) {
      bf16x8 af = *(const bf16x8*)((char*)sb2 + ((l15 * 128 + ks * 64 + lg * 16) ^ ((l15 & 7) << 4)));
#pragma unroll
      for (int nt = 0; nt < 8; ++nt) {
        int c = w * 128 + nt * 16 + l15;
        bf16x8 bfr = *(const bf16x8*)(Wi1sb + (size_t)c * 64 + ks * 32 + lg * 8);
        a4[nt] = __builtin_amdgcn_mfma_f32_16x16x32_bf16(af, bfr, a4[nt], 0, 0, 0);
      }
    }
#pragma unroll
    for (int nt = 0; nt < 8; ++nt) {
      int c = w * 128 + nt * 16 + l15;
      float bb = bi1s[c];
#pragma unroll
      for (int r = 0; r < 4; ++r)
        sp[(size_t)(b0 + 4 * lg + r) * 512 + c] = a4[nt][r] + bb;
    }
  }
}

// ---------------- big6: swapped-operand 32x32 GEMM1 + depth-4 B prefetch ------
// BM=64 (1 batch row), BN=512, 8 waves. A-panel h1[64][512] in LDS (&15 swizzle).
// GEMM1 computes mfma(Wi2frag, h1frag): C/D col=lane&31 -> p (h1 row),
// reg -> c (Wi2 row) => each reg quad = 4 consecutive h2 COLUMNS of one row
// => epilogue packs to ds_write_b64 (4x fewer LDS issues than b16 scatter).
// B(Wi2) fragments stream from L2 with a 4-deep statically-indexed prefetch.
__global__ __launch_bounds__(512, 4) void big6_kernel(
    const float* __restrict__ a_bits, const float* __restrict__ sp,
    const float* __restrict__ Wi1posT,
    const ushort_t* __restrict__ Wi2f32, const ushort_t* __restrict__ Wi3f,
    const float* __restrict__ bi2, const float* __restrict__ bi3,
    float* __restrict__ out) {
  __shared__ __align__(16) ushort_t h1s[64 * 512];   // 64KB, reused as h2
  __shared__ float bi2s[512];
  __shared__ float ab[64];
  __shared__ float bi3s[64];

  int b = blockIdx.x, t = threadIdx.x;
  int w = t >> 6, l = t & 63, lg = l >> 4, l15 = l & 15;
  int l31 = l & 31, hi = l >> 5;

  bi2s[t] = bi2[t];
  if (t < 64) { ab[t] = a_bits[b * 64 + t]; bi3s[t] = bi3[t]; }

  // ---- phase 0: h1[64][512] = relu(sp[b] + pos) -> LDS bf16, swizzled, ONCE ----
  {
    const float* sprow = sp + (size_t)b * 512 + l * 8;
    float4 s0 = *(const float4*)(sprow);
    float4 s1 = *(const float4*)(sprow + 4);
#pragma unroll
    for (int g = 0; g < 8; ++g) {
      int p = g * 8 + w;                    // wave w covers rows {w, 8+w, ..., 56+w}
      const float4* pr = (const float4*)(Wi1posT + (size_t)p * 512 + l * 8);
      float4 p0 = pr[0], p1 = pr[1];
      float v0 = fmaxf(s0.x + p0.x, 0.f), v1 = fmaxf(s0.y + p0.y, 0.f);
      float v2 = fmaxf(s0.z + p0.z, 0.f), v3 = fmaxf(s0.w + p0.w, 0.f);
      float v4 = fmaxf(s1.x + p1.x, 0.f), v5 = fmaxf(s1.y + p1.y, 0.f);
      float v6 = fmaxf(s1.z + p1.z, 0.f), v7 = fmaxf(s1.w + p1.w, 0.f);
      uint4 pk;
      pk.x = pack2bf(v0, v1); pk.y = pack2bf(v2, v3);
      pk.z = pack2bf(v4, v5); pk.w = pack2bf(v6, v7);
      *(uint4*)((char*)h1s + ((p * 1024 + l * 16) ^ ((p & 15) << 4))) = pk;
    }
  }
  __syncthreads();

  // ---- GEMM1: h2^T tiles = Wi2 @ h1^T ; 32x32x16, depth-4 B prefetch ----
  f32x16 acc[2][2];   // acc[mc][np]: c-tile mc (reg axis), p-tile np (lane axis)
#pragma unroll
  for (int mc = 0; mc < 2; ++mc)
#pragma unroll
    for (int np = 0; np < 2; ++np)
#pragma unroll
      for (int r = 0; r < 16; ++r) acc[mc][np][r] = 0.f;

  // frag (ks, ct) at bf16x8 index (ks*16+ct)*64 + l ; wave w: ct = 2w+mc
  const bf16x8* bbase = (const bf16x8*)Wi2f32 + ((size_t)(2 * w) * 64 + l);
  bf16x8 wf[4][2];
#pragma unroll
  for (int d = 0; d < 4; ++d) {
    wf[d][0] = bbase[(size_t)d * 1024];
    wf[d][1] = bbase[(size_t)d * 1024 + 64];
  }

  for (int kb = 0; kb < 8; ++kb) {
#pragma unroll
    for (int d = 0; d < 4; ++d) {
      int ks = kb * 4 + d;
      bf16x8 w0 = wf[d][0], w1 = wf[d][1];
      if (kb < 7) {
        wf[d][0] = bbase[(size_t)(ks + 4) * 1024];
        wf[d][1] = bbase[(size_t)(ks + 4) * 1024 + 64];
      }
      int row0 = l31, row1 = 32 + l31;
      bf16x8 h0 = *(const bf16x8*)((char*)h1s + ((row0 * 1024 + ks * 32 + hi * 16) ^ ((row0 & 15) << 4)));
      bf16x8 h1v = *(const bf16x8*)((char*)h1s + ((row1 * 1024 + ks * 32 + hi * 16) ^ ((row1 & 15) << 4)));
      acc[0][0] = __builtin_amdgcn_mfma_f32_32x32x16_bf16(w0, h0, acc[0][0], 0, 0, 0);
      acc[0][1] = __builtin_amdgcn_mfma_f32_32x32x16_bf16(w0, h1v, acc[0][1], 0, 0, 0);
      acc[1][0] = __builtin_amdgcn_mfma_f32_32x32x16_bf16(w1, h0, acc[1][0], 0, 0, 0);
      acc[1][1] = __builtin_amdgcn_mfma_f32_32x32x16_bf16(w1, h1v, acc[1][1], 0, 0, 0);
    }
  }
  __syncthreads();   // everyone done reading h1s

  // ---- h2 = relu(acc + bi2) -> h1s region, ds_write_b64 packed ----
  // p = np*32 + l31 ; c = w*64 + mc*32 + (r&3) + 8*(r>>2) + 4*hi
#pragma unroll
  for (int mc = 0; mc < 2; ++mc) {
#pragma unroll
    for (int np = 0; np < 2; ++np) {
      int p = np * 32 + l31;
#pragma unroll
      for (int rq = 0; rq < 4; ++rq) {
        int c0 = w * 64 + mc * 32 + 8 * rq + 4 * hi;
        float4 bi4 = *(const float4*)(bi2s + c0);
        float v0 = fmaxf(acc[mc][np][4 * rq + 0] + bi4.x, 0.f);
        float v1 = fmaxf(acc[mc][np][4 * rq + 1] + bi4.y, 0.f);
        float v2 = fmaxf(acc[mc][np][4 * rq + 2] + bi4.z, 0.f);
        float v3 = fmaxf(acc[mc][np][4 * rq + 3] + bi4.w, 0.f);
        uint2 pk;
        pk.x = pack2bf(v0, v1);
        pk.y = pack2bf(v2, v3);
        *(uint2*)((char*)h1s + ((p * 1024 + c0 * 2) ^ ((p & 15) << 4))) = pk;
      }
    }
  }
  __syncthreads();

  // ---- GEMM2 (waves 0-3): logits[64][64] = h2 @ Wi3^T, frag-order Wi3f (16x16) ----
  if (w < 4) {
    f32x4 lacc[4];
#pragma unroll
    for (int n = 0; n < 4; ++n) lacc[n] = (f32x4){0.f, 0.f, 0.f, 0.f};
    int p2 = 16 * w + l15;
    const bf16x8* b3base = (const bf16x8*)Wi3f + l;
#pragma unroll 4
    for (int ks2 = 0; ks2 < 16; ++ks2) {
      bf16x8 a2 = *(const bf16x8*)((char*)h1s + ((p2 * 1024 + ks2 * 64 + lg * 16) ^ ((p2 & 15) << 4)));
#pragma unroll
      for (int nt2 = 0; nt2 < 4; ++nt2) {
        bf16x8 b2v = b3base[(ks2 * 4 + nt2) * 64];
        lacc[nt2] = __builtin_amdgcn_mfma_f32_16x16x32_bf16(a2, b2v, lacc[nt2], 0, 0, 0);
      }
    }

    // ---- epilogue: per-row softmax over 64 logits + gather-sum with a_bits ----
#pragma unroll
    for (int r = 0; r < 4; ++r) {
      float v[4];
      float m = -1e30f;
#pragma unroll
      for (int nt2 = 0; nt2 < 4; ++nt2) {
        v[nt2] = lacc[nt2][r] + bi3s[nt2 * 16 + l15];
        m = fmaxf(m, v[nt2]);
      }
#pragma unroll
      for (int mm = 8; mm >= 1; mm >>= 1) m = fmaxf(m, __shfl_xor(m, mm));
      float s = 0.f, g = 0.f;
#pragma unroll
      for (int nt2 = 0; nt2 < 4; ++nt2) {
        float e = expf(v[nt2] - m);
        s += e;
        g += e * ab[nt2 * 16 + l15];
      }
#pragma unroll
      for (int mm = 8; mm >= 1; mm >>= 1) { s += __shfl_xor(s, mm); g += __shfl_xor(g, mm); }
      if (l15 == 0) out[b * 64 + 16 * w + 4 * lg + r] = g / s;
    }
  }
}

extern "C" void kernel_launch(void* const* d_in, const int* in_sizes, int n_in,
                              void* d_out, int out_size, void* d_ws, size_t ws_size,
                              hipStream_t stream) {
  const float* a_bits     = (const float*)d_in[0];
  const float* shift_bits = (const float*)d_in[1];
  const float* W1  = (const float*)d_in[2];
  const float* b1  = (const float*)d_in[3];
  const float* g1  = (const float*)d_in[4];
  const float* be1 = (const float*)d_in[5];
  const float* W2  = (const float*)d_in[6];
  const float* b2  = (const float*)d_in[7];
  const float* g2  = (const float*)d_in[8];
  const float* be2 = (const float*)d_in[9];
  const float* W3  = (const float*)d_in[10];
  const float* b3  = (const float*)d_in[11];
  const float* Wi1 = (const float*)d_in[12];
  const float* bi1 = (const float*)d_in[13];
  const float* Wi2 = (const float*)d_in[14];
  const float* bi2 = (const float*)d_in[15];
  const float* Wi3 = (const float*)d_in[16];
  const float* bi3 = (const float*)d_in[17];
  float* out = (float*)d_out;

  // ws layout: sp fp32 [B][512] (8MB) | W2b (512KB) | W1b (64KB) | W3b (64KB)
  //            | Wi1sb (64KB) | Wi1posT fp32 (128KB) | Wi2f32 (512KB) | Wi3f (64KB)
  float* sp = (float*)d_ws;
  ushort_t* W2b = (ushort_t*)((char*)d_ws + (size_t)B_N * HID * 4);
  ushort_t* W1b = W2b + 512 * 512;
  ushort_t* W3b = W1b + 512 * 64;
  ushort_t* Wi1sb = W3b + 64 * 512;
  float* Wi1posT = (float*)(Wi1sb + 512 * 64);
  ushort_t* Wi2f32 = (ushort_t*)(Wi1posT + 64 * 512);
  ushort_t* Wi3f = Wi2f32 + 512 * 512;

  prep_kernel<<<1024, 256, 0, stream>>>(Wi2, Wi3, Wi1, W1, W2, W3,
                                        Wi1posT, W1b, W2b, W3b, Wi1sb, Wi2f32, Wi3f);
  shift2_kernel<<<B_N / BT, 256, 0, stream>>>(shift_bits, W1b, b1, g1, be1,
                                              W2b, b2, g2, be2, W3b, b3, Wi1sb, bi1, sp);
  big6_kernel<<<B_N, 512, 0, stream>>>(a_bits, sp, Wi1posT, Wi2f32, Wi3f, bi2, bi3, out);
}